// Round 21
// baseline (1092.355 us; speedup 1.0000x reference)
//
#include <hip/hip_runtime.h>
#include <hip/hip_bf16.h>

// ---------------------------------------------------------------------------
// TransformerSquared forward on MI355X.
// R20 = R19 base; remaining 2-barrier U-GEMMs (pU, f2U: MODE2; f1U: MODE1,
// all K=256) switched to the verified barrier-free 1-wave gemm1w structure.
// ---------------------------------------------------------------------------

#define T_SEQ 2048
#define DMODEL 1024
#define NHEAD 16
#define HSZ 64
#define NLAYER 4
#define FFDIM 4096
#define RH 16
#define RP 256
#define RF 256
#define VOCAB 32000
#define NKQV (3 * NHEAD * RH) // 768

typedef short short8 __attribute__((ext_vector_type(8)));
typedef float f32x4 __attribute__((ext_vector_type(4)));
typedef unsigned int uint_t;
typedef unsigned short ushort_t;

__device__ __forceinline__ float bfbits2f(uint_t bits16_in_low) {
    uint_t b = bits16_in_low << 16;
    float f;
    __builtin_memcpy(&f, &b, 4);
    return f;
}
__device__ __forceinline__ ushort_t f2bfu(float f) {
    union { __hip_bfloat16 b; ushort_t u; } cv;
    cv.b = __float2bfloat16(f);
    return cv.u;
}
__device__ __forceinline__ uint_t pack2bf(float a, float b) {
    return (uint_t)f2bfu(a) | ((uint_t)f2bfu(b) << 16);
}

// async global->LDS, 16 bytes per lane. LDS dest = wave-uniform base + lane*16.
__device__ __forceinline__ void gld16(const __hip_bfloat16* g, short* l) {
    __builtin_amdgcn_global_load_lds(
        (const __attribute__((address_space(1))) void*)g,
        (__attribute__((address_space(3))) void*)l, 16, 0, 0);
}

// ----------------------- batched f32 -> bf16 convert -----------------------
struct CvtArgs {
    const float* s[9];
    __hip_bfloat16* d[9];
    int n4[9];
};
__global__ __launch_bounds__(256) void cvtall_k(CvtArgs a, int total4) {
    int i = blockIdx.x * 256 + threadIdx.x;
    if (i >= total4) return;
#pragma unroll
    for (int k = 0; k < 9; ++k) {
        if (i < a.n4[k]) {
            float4 v = ((const float4*)a.s[k])[i];
            ushort4 o;
            o.x = f2bfu(v.x); o.y = f2bfu(v.y); o.z = f2bfu(v.z); o.w = f2bfu(v.w);
            ((ushort4*)a.d[k])[i] = o;
            return;
        }
        i -= a.n4[k];
    }
}

// ------------------------------- embedding ---------------------------------
__global__ __launch_bounds__(256) void embed_k(const int* __restrict__ idx,
                                               const float* __restrict__ tok,
                                               const float* __restrict__ pos,
                                               float* __restrict__ x) {
    int i = blockIdx.x * 256 + threadIdx.x;          // over T*D/4
    int d4 = i & (DMODEL / 4 - 1);
    int t = i >> 8;                                   // D/4 = 256
    int tk = idx[t];
    float4 a = ((const float4*)(tok + (size_t)tk * DMODEL))[d4];
    float4 p = ((const float4*)(pos + (size_t)t * DMODEL))[d4];
    a.x += p.x; a.y += p.y; a.z += p.z; a.w += p.w;
    ((float4*)(x + (size_t)t * DMODEL))[d4] = a;
}

// ------------------------------- layernorm ---------------------------------
__global__ __launch_bounds__(256) void ln_k(const float* __restrict__ xin,
                                            const float* __restrict__ w,
                                            const float* __restrict__ b,
                                            __hip_bfloat16* __restrict__ out) {
    const int row = blockIdx.x, tid = threadIdx.x;
    const float4 v = ((const float4*)(xin + (size_t)row * DMODEL))[tid];
    float s = v.x + v.y + v.z + v.w;
    float q = v.x * v.x + v.y * v.y + v.z * v.z + v.w * v.w;
    for (int off = 32; off; off >>= 1) { s += __shfl_xor(s, off); q += __shfl_xor(q, off); }
    __shared__ float rs_[4], rq_[4];
    if ((tid & 63) == 0) { rs_[tid >> 6] = s; rq_[tid >> 6] = q; }
    __syncthreads();
    s = rs_[0] + rs_[1] + rs_[2] + rs_[3];
    q = rq_[0] + rq_[1] + rq_[2] + rq_[3];
    const float mean = s * (1.f / DMODEL);
    const float var = q * (1.f / DMODEL) - mean * mean;
    const float rstd = rsqrtf(var + 1e-5f);
    const float4 wv = ((const float4*)w)[tid];
    const float4 bv = ((const float4*)b)[tid];
    ushort4 o;
    o.x = f2bfu((v.x - mean) * rstd * wv.x + bv.x);
    o.y = f2bfu((v.y - mean) * rstd * wv.y + bv.y);
    o.z = f2bfu((v.z - mean) * rstd * wv.z + bv.z);
    o.w = f2bfu((v.w - mean) * rstd * wv.w + bv.w);
    ((ushort4*)out)[(size_t)row * (DMODEL / 4) + tid] = o;
}

// --------------------------- generic GEMM (A * B^T) ------------------------
// m97-structure, 2-barrier, both-sides XOR swizzle (verified 0 conflicts R4).
template <int BM, int BN, int MODE>
__global__ __launch_bounds__(256) void gemm_t(const __hip_bfloat16* __restrict__ A,
                                              const __hip_bfloat16* __restrict__ B,
                                              const float* __restrict__ colscale,
                                              __hip_bfloat16* __restrict__ Cb,
                                              float* __restrict__ Cf,
                                              int M, int N, int K) {
    constexpr int WM = (BN >= 128) ? 2 : 4;
    constexpr int WN = 4 / WM;
    constexpr int TM = BM / WM / 16;
    constexpr int TN = BN / WN / 16;
    constexpr int IA = BM / 32;     // gld16 iters for A tile
    constexpr int IB = BN / 32;
    __shared__ short As[BM * 64];
    __shared__ short Bs[BN * 64];
    const int tid = threadIdx.x;
    const int w = tid >> 6, ln = tid & 63, lr = ln & 15, lg = ln >> 4;
    const int GM = M / BM;

    const int nwg = gridDim.x;
    const int cpx = nwg >> 3;
    const int wg = (blockIdx.x & 7) * cpx + (blockIdx.x >> 3);
    const int bm = wg % GM, bn = wg / GM;
    const int wm = w / WN, wn = w % WN;

    f32x4 acc[TM][TN] = {};

    const int srow = tid >> 3;
    const int scol = (((tid & 7) ^ ((tid >> 3) & 7)) * 8);
    const __hip_bfloat16* Ag = A + (size_t)(bm * BM + srow) * K + scol;
    const __hip_bfloat16* Bg = B + (size_t)(bn * BN + srow) * K + scol;

    for (int kt = 0; kt < K; kt += 64) {
        __syncthreads();   // previous tile consumed
#pragma unroll
        for (int i = 0; i < IA; ++i)
            gld16(Ag + (size_t)(i * 32) * K + kt, &As[i * 2048 + w * 512]);
#pragma unroll
        for (int i = 0; i < IB; ++i)
            gld16(Bg + (size_t)(i * 32) * K + kt, &Bs[i * 2048 + w * 512]);
        __syncthreads();   // drains vmcnt + barrier

#pragma unroll
        for (int kk = 0; kk < 2; ++kk) {
            short8 af[TM], bf[TN];
#pragma unroll
            for (int m = 0; m < TM; ++m) {
                const int row = wm * (BM / WM) + m * 16 + lr;
                af[m] = *(const short8*)&As[row * 64 + (((kk * 4 + lg) ^ (lr & 7)) * 8)];
            }
#pragma unroll
            for (int n = 0; n < TN; ++n) {
                const int row = wn * (BN / WN) + n * 16 + lr;
                bf[n] = *(const short8*)&Bs[row * 64 + (((kk * 4 + lg) ^ (lr & 7)) * 8)];
            }
#pragma unroll
            for (int m = 0; m < TM; ++m)
#pragma unroll
                for (int n = 0; n < TN; ++n)
                    acc[m][n] = __builtin_amdgcn_mfma_f32_16x16x32_bf16(af[m], bf[n], acc[m][n], 0, 0, 0);
        }
    }

#pragma unroll
    for (int n = 0; n < TN; ++n) {
        const int col = bn * BN + wn * (BN / WN) + n * 16 + lr;
        float cs = 1.0f;
        if (MODE == 0 && colscale) cs = colscale[col];
#pragma unroll
        for (int m = 0; m < TM; ++m) {
#pragma unroll
            for (int rr = 0; rr < 4; ++rr) {
                const int row = bm * BM + wm * (BM / WM) + m * 16 + lg * 4 + rr;
                float v = acc[m][n][rr];
                const size_t o = (size_t)row * N + col;
                if (MODE == 0) {
                    Cb[o] = __float2bfloat16(v * cs);
                } else if (MODE == 1) {
                    v = 0.5f * v * (1.0f + erff(v * 0.70710678118654752f));
                    Cb[o] = __float2bfloat16(v);
                } else if (MODE == 2) {
                    Cf[o] += v;
                } else {
                    Cf[o] = v;
                }
            }
        }
    }
}

// ------------- 1-wave 64x64 GEMM, ring-2 counted vmcnt, no barriers --------
// For K-deep / latency-bound GEMMs. Single wave => all sync is program-order
// s_waitcnt: vmcnt(16) proves tile t staged; lgkmcnt(0)+clobber before the
// STAGE that overwrites the buffer just read.
template <int MODE>
__global__ __launch_bounds__(64) void gemm1w(const __hip_bfloat16* __restrict__ A,
                                             const __hip_bfloat16* __restrict__ B,
                                             const float* __restrict__ colscale,
                                             __hip_bfloat16* __restrict__ Cb,
                                             float* __restrict__ Cf,
                                             int M, int N, int K) {
    __shared__ short As[2][64 * 64];
    __shared__ short Bs[2][64 * 64];
    const int tid = threadIdx.x;          // 0..63
    const int lr = tid & 15, lg = tid >> 4;
    const int GM = M / 64;

    const int nwg = gridDim.x;            // divisible by 8
    const int cpx = nwg >> 3;
    const int wg = (blockIdx.x & 7) * cpx + (blockIdx.x >> 3);
    const int bm = wg % GM, bn = wg / GM;

    const int srow = tid >> 3;            // 0..7
    const int scol = ((tid & 7) ^ srow) * 8;
    const __hip_bfloat16* Ag = A + (size_t)(bm * 64 + srow) * K + scol;
    const __hip_bfloat16* Bg = B + (size_t)(bn * 64 + srow) * K + scol;

    f32x4 acc[4][4] = {};

    auto STAGE = [&](int t) {
        const int b = t & 1;
        const size_t ko = (size_t)t * 64;
#pragma unroll
        for (int i = 0; i < 8; ++i) {
            gld16(Ag + (size_t)(i * 8) * K + ko, &As[b][i * 512]);
            gld16(Bg + (size_t)(i * 8) * K + ko, &Bs[b][i * 512]);
        }
    };

    STAGE(0); STAGE(1);                   // 32 outstanding

    const int T = K / 64;
    for (int t = 0; t < T; ++t) {
        if (t < T - 1) asm volatile("s_waitcnt vmcnt(16)" ::: "memory");
        else           asm volatile("s_waitcnt vmcnt(0)" ::: "memory");
        const short* Ab = As[t & 1];
        const short* Bb = Bs[t & 1];
        short8 af0[4], bf0[4], af1[4], bf1[4];
#pragma unroll
        for (int m = 0; m < 4; ++m) {
            const int R = m * 16 + lr;
            af0[m] = *(const short8*)&Ab[R * 64 + ((lg ^ (lr & 7)) * 8)];
            af1[m] = *(const short8*)&Ab[R * 64 + (((4 + lg) ^ (lr & 7)) * 8)];
            bf0[m] = *(const short8*)&Bb[R * 64 + ((lg ^ (lr & 7)) * 8)];
            bf1[m] = *(const short8*)&Bb[R * 64 + (((4 + lg) ^ (lr & 7)) * 8)];
        }
        asm volatile("s_waitcnt lgkmcnt(0)" ::: "memory");  // reads done
        if (t + 2 < T) STAGE(t + 2);       // safe: buffer fully consumed
        __builtin_amdgcn_sched_barrier(0);
#pragma unroll
        for (int m = 0; m < 4; ++m)
#pragma unroll
            for (int n = 0; n < 4; ++n)
                acc[m][n] = __builtin_amdgcn_mfma_f32_16x16x32_bf16(af0[m], bf0[n], acc[m][n], 0, 0, 0);
#pragma unroll
        for (int m = 0; m < 4; ++m)
#pragma unroll
            for (int n = 0; n < 4; ++n)
                acc[m][n] = __builtin_amdgcn_mfma_f32_16x16x32_bf16(af1[m], bf1[n], acc[m][n], 0, 0, 0);
    }

#pragma unroll
    for (int n = 0; n < 4; ++n) {
        const int col = bn * 64 + n * 16 + lr;
        float cs = 1.0f;
        if (MODE == 0 && colscale) cs = colscale[col];
#pragma unroll
        for (int m = 0; m < 4; ++m) {
#pragma unroll
            for (int rr = 0; rr < 4; ++rr) {
                const int row = bm * 64 + m * 16 + lg * 4 + rr;
                float v = acc[m][n][rr];
                const size_t o = (size_t)row * N + col;
                if (MODE == 0) {
                    Cb[o] = __float2bfloat16(v * cs);
                } else if (MODE == 1) {
                    v = 0.5f * v * (1.0f + erff(v * 0.70710678118654752f));
                    Cb[o] = __float2bfloat16(v);
                } else if (MODE == 2) {
                    Cf[o] += v;
                } else {
                    Cf[o] = v;
                }
            }
        }
    }
}

// ---------------- logits GEMM: 256x256, counted-vmcnt pipeline -------------
// (R12-verified: ~181us, MfmaUtil 31%, 0 conflicts — empirical best)
__global__ __launch_bounds__(512, 2) void gemm256l(const __hip_bfloat16* __restrict__ A,
                                                   const __hip_bfloat16* __restrict__ B,
                                                   float* __restrict__ C,
                                                   int M, int N, int K) {
    __shared__ short As[2][256 * 64];
    __shared__ short Bs[2][256 * 64];
    const int tid = threadIdx.x;
    const int w = tid >> 6, ln = tid & 63, lr = ln & 15, lg = ln >> 4;
    const int wm = w >> 2, wn = w & 3;
    const int GM = M / 256;              // 8

    const int nwg = gridDim.x;           // 1000
    const int cpx = nwg >> 3;            // 125
    const int wg = (blockIdx.x & 7) * cpx + (blockIdx.x >> 3);
    const int bm = wg % GM, bn = wg / GM;

    const int srow = tid >> 3;           // 0..63
    const int scol = (((tid & 7) ^ ((tid >> 3) & 7)) * 8);
    const __hip_bfloat16* Ag = A + (size_t)(bm * 256 + srow) * K + scol;
    const __hip_bfloat16* Bg = B + (size_t)(bn * 256 + srow) * K + scol;
    const int ldsb = w * 512;            // shorts; wave-uniform

    f32x4 acc[8][4] = {};

    auto STAGE = [&](int t) {
        const int b = t & 1;
        const size_t ko = (size_t)t * 64;
#pragma unroll
        for (int i = 0; i < 4; ++i) {
            gld16(Ag + (size_t)(i * 64) * K + ko, &As[b][i * 4096 + ldsb]);
            gld16(Bg + (size_t)(i * 64) * K + ko, &Bs[b][i * 4096 + ldsb]);
        }
    };

    STAGE(0); STAGE(1);                   // 16 vmem / wave outstanding

    const int T = K / 64;                 // 16
    for (int t = 0; t < T; ++t) {
        if (t < T - 1) asm volatile("s_waitcnt vmcnt(8)" ::: "memory");
        else           asm volatile("s_waitcnt vmcnt(0)" ::: "memory");
        __builtin_amdgcn_s_barrier();     // tile t present in buf[t&1]

        const short* Ab = As[t & 1];
        const short* Bb = Bs[t & 1];
        short8 af0[8], bf0[4], af1[8], bf1[4];
#pragma unroll
        for (int m = 0; m < 8; ++m) {
            const int R = wm * 128 + m * 16 + lr;
            af0[m] = *(const short8*)&Ab[R * 64 + ((lg ^ (lr & 7)) * 8)];
        }
#pragma unroll
        for (int n = 0; n < 4; ++n) {
            const int R = wn * 64 + n * 16 + lr;
            bf0[n] = *(const short8*)&Bb[R * 64 + ((lg ^ (lr & 7)) * 8)];
        }
        // kk0 MFMAs (compiler may overlap kk1 reads below with these)
#pragma unroll
        for (int m = 0; m < 8; ++m)
#pragma unroll
            for (int n = 0; n < 4; ++n)
                acc[m][n] = __builtin_amdgcn_mfma_f32_16x16x32_bf16(af0[m], bf0[n], acc[m][n], 0, 0, 0);
#pragma unroll
        for (int m = 0; m < 8; ++m) {
            const int R = wm * 128 + m * 16 + lr;
            af1[m] = *(const short8*)&Ab[R * 64 + (((4 + lg) ^ (lr & 7)) * 8)];
        }
#pragma unroll
        for (int n = 0; n < 4; ++n) {
            const int R = wn * 64 + n * 16 + lr;
            bf1[n] = *(const short8*)&Bb[R * 64 + (((4 + lg) ^ (lr & 7)) * 8)];
        }
        asm volatile("s_waitcnt lgkmcnt(0)" ::: "memory");
        __builtin_amdgcn_s_barrier();     // all waves done reading buf[t&1]
        if (t + 2 < T) STAGE(t + 2);      // overwrite buf[t&1] (safe)
        __builtin_amdgcn_sched_barrier(0);
        __builtin_amdgcn_s_setprio(1);
#pragma unroll
        for (int m = 0; m < 8; ++m)
#pragma unroll
            for (int n = 0; n < 4; ++n)
                acc[m][n] = __builtin_amdgcn_mfma_f32_16x16x32_bf16(af1[m], bf1[n], acc[m][n], 0, 0, 0);
        __builtin_amdgcn_s_setprio(0);
    }

#pragma unroll
    for (int m = 0; m < 8; ++m) {
        const int row = bm * 256 + wm * 128 + m * 16 + lg * 4;
#pragma unroll
        for (int rr = 0; rr < 4; ++rr) {
            float* crow = C + (size_t)(row + rr) * N + bn * 256 + wn * 64 + lr;
#pragma unroll
            for (int n = 0; n < 4; ++n)
                crow[n * 16] = acc[m][n][rr];
        }
    }
}

// ------------- per-head SVF U-projection (K=16) + layout fusion ------------
__global__ __launch_bounds__(256) void kqv2_k(const __hip_bfloat16* __restrict__ t1,
                                              const __hip_bfloat16* __restrict__ U,
                                              __hip_bfloat16* __restrict__ qb,
                                              __hip_bfloat16* __restrict__ kb2,
                                              __hip_bfloat16* __restrict__ vt2) {
    size_t i = (size_t)blockIdx.x * 256 + threadIdx.x; // 3*16*2048*64
    int s = (int)(i & 63);
    size_t rest = i >> 6;
    int t = (int)(rest & (T_SEQ - 1));
    int gh = (int)(rest >> 11);                        // 0..47, g-major
    const short8* trow = (const short8*)(t1 + (size_t)t * NKQV + gh * RH);
    const short8* urow = (const short8*)(U + ((size_t)gh * HSZ + s) * RH);
    short8 ta = trow[0], tb = trow[1];
    short8 ua = urow[0], ub = urow[1];
    float acc = 0.f;
#pragma unroll
    for (int j = 0; j < 8; ++j) {
        acc += bfbits2f((ushort_t)ta[j]) * bfbits2f((ushort_t)ua[j]);
        acc += bfbits2f((ushort_t)tb[j]) * bfbits2f((ushort_t)ub[j]);
    }
    const ushort_t val = f2bfu(acc);
    const int g = gh >> 4, h = gh & 15;               // block-uniform g
    if (g == 1) {
        ((ushort_t*)qb)[((size_t)h * T_SEQ + t) * HSZ + s] = val;
    } else if (g == 0) {
        const int tile = t >> 6, gg = (t >> 4) & 3, lr = t & 15;
        const int half = s >> 5, lg = (s >> 3) & 3, j = s & 7;
        const int c = gg * 2 + half, ln = lg * 16 + lr;
        ((ushort_t*)kb2)[(((size_t)h * 32 + tile) * 8 + c) * 512 + ln * 8 + j] = val;
    } else {
        const int tile = t >> 6, half = (t >> 5) & 1, lg2 = (t >> 3) & 3, j2 = t & 7;
        const int dt = s >> 4, lr2 = s & 15;
        const int c = dt * 2 + half, ln = lg2 * 16 + lr2;
        ((ushort_t*)vt2)[(((size_t)h * 32 + tile) * 8 + c) * 512 + ln * 8 + j2] = val;
    }
}

// --------------------------- MFMA flash attention --------------------------
// KVBLK=128 (two chunk-tiles per softmax round). Masked-tail pair +
// defer-max (T13).
__global__ __launch_bounds__(256) void attn_k(const __hip_bfloat16* __restrict__ qb,
                                              const __hip_bfloat16* __restrict__ kb2,
                                              const __hip_bfloat16* __restrict__ vt2,
                                              __hip_bfloat16* __restrict__ attout) {
    __shared__ short P_s[2][4][16 * 136];  // [dbuf][wave][16 q x 128 u], stride 136
    const int tid = threadIdx.x, w = tid >> 6, ln = tid & 63;
    const int lr = ln & 15, lg = ln >> 4;
    const int f = blockIdx.y * 32 + blockIdx.x;
    const int h = ((f & 7) << 1) | ((f >> 3) & 1);
    const int bi = f >> 4;
    const int t0 = bi * 16 + w * 512;
    const size_t hb = (size_t)h * T_SEQ;
    const size_t hB = (size_t)h * 32;   // tile base for chunk addressing
    const float SCL = 0.18033688011112042f; // 0.125 * log2(e)

    short8 qf0 = *(const short8*)(qb + (hb + t0 + lr) * HSZ + lg * 8);
    short8 qf1 = *(const short8*)(qb + (hb + t0 + lr) * HSZ + 32 + lg * 8);

    f32x4 acc[4] = {};
    float mrun = -3e38f, lrun = 0.f;
    int pbuf = 0;

    short8 kf[8][2];
#pragma unroll
    for (int c = 0; c < 8; ++c) {
        kf[c][0] = *(const short8*)(kb2 + ((hB + (c >> 2)) * 8 + (c & 3) * 2 + 0) * 512 + (size_t)ln * 8);
        kf[c][1] = *(const short8*)(kb2 + ((hB + (c >> 2)) * 8 + (c & 3) * 2 + 1) * 512 + (size_t)ln * 8);
    }

    const int last = t0 >> 7;             // index of the final 128-pair
    for (int it2 = 0; it2 <= last; ++it2) {
        f32x4 st[8];
#pragma unroll
        for (int c = 0; c < 8; ++c) {
            f32x4 z = {};
            z = __builtin_amdgcn_mfma_f32_16x16x32_bf16(kf[c][0], qf0, z, 0, 0, 0);
            st[c] = __builtin_amdgcn_mfma_f32_16x16x32_bf16(kf[c][1], qf1, z, 0, 0, 0);
        }

        if (it2 < last) {                 // prefetch next pair
            const int tn = (it2 + 1) * 2;
#pragma unroll
            for (int c = 0; c < 8; ++c) {
                kf[c][0] = *(const short8*)(kb2 + ((hB + tn + (c >> 2)) * 8 + (c & 3) * 2 + 0) * 512 + (size_t)ln * 8);
                kf[c][1] = *(const short8*)(kb2 + ((hB + tn + (c >> 2)) * 8 + (c & 3) * 2 + 1) * 512 + (size_t)ln * 8);
            }
        }

        float sv[32];
        if (it2 == last) {                // only the final pair needs masking
            const int u0 = it2 * 128;
            const int qg = t0 + lr;
#pragma unroll
            for (int c = 0; c < 8; ++c)
#pragma unroll
                for (int r = 0; r < 4; ++r) {
                    float v = st[c][r] * SCL;
                    if (u0 + c * 16 + lg * 4 + r > qg) v = -1e30f;
                    sv[c * 4 + r] = v;
                }
        } else {
#pragma unroll
            for (int c = 0; c < 8; ++c)
#pragma unroll
                for (int r = 0; r < 4; ++r)
                    sv[c * 4 + r] = st[c][r] * SCL;
        }

        float mm[8];
#pragma unroll
        for (int c = 0; c < 8; ++c)
            mm[c] = fmaxf(fmaxf(sv[c * 4], sv[c * 4 + 1]), fmaxf(sv[c * 4 + 2], sv[c * 4 + 3]));
        float tm = fmaxf(fmaxf(fmaxf(mm[0], mm[1]), fmaxf(mm[2], mm[3])),
                         fmaxf(fmaxf(mm[4], mm[5]), fmaxf(mm[6], mm[7])));
        tm = fmaxf(tm, __shfl_xor(tm, 16));
        tm = fmaxf(tm, __shfl_xor(tm, 32));

        if (!__all(tm - mrun <= 8.0f)) {  // defer-max (T13)
            const float mnew = fmaxf(mrun, tm);
            const float corr = exp2f(mrun - mnew);
            lrun *= corr;
#pragma unroll
            for (int dt = 0; dt < 4; ++dt) acc[dt] *= corr;
            mrun = mnew;
        }

        float pv[32];
        float ls = 0.f;
#pragma unroll
        for (int j = 0; j < 32; ++j) { pv[j] = exp2f(sv[j] - mrun); ls += pv[j]; }
        ls += __shfl_xor(ls, 16);
        ls += __shfl_xor(ls, 32);
        lrun += ls;

        uint_t* pw = (uint_t*)P_s[pbuf][w];
        const int wb = lr * 68 + lg * 2;
#pragma unroll
        for (int c = 0; c < 8; ++c) {
            pw[wb + c * 8 + 0] = pack2bf(pv[c * 4 + 0], pv[c * 4 + 1]);
            pw[wb + c * 8 + 1] = pack2bf(pv[c * 4 + 2], pv[c * 4 + 3]);
        }
        asm volatile("s_waitcnt lgkmcnt(0)" ::: "memory");

#pragma unroll
        for (int s = 0; s < 2; ++s) {
            short8 vfs[4][2];
#pragma unroll
            for (int dt = 0; dt < 4; ++dt) {
                vfs[dt][0] = *(const short8*)(vt2 + ((hB + it2 * 2 + s) * 8 + dt * 2 + 0) * 512 + (size_t)ln * 8);
                vfs[dt][1] = *(const short8*)(vt2 + ((hB + it2 * 2 + s) * 8 + dt * 2 + 1) * 512 + (size_t)ln * 8);
            }
            short8 pf0 = *(const short8*)(&P_s[pbuf][w][lr * 136 + s * 64 + lg * 8]);
            short8 pf1 = *(const short8*)(&P_s[pbuf][w][lr * 136 + s * 64 + 32 + lg * 8]);
#pragma unroll
            for (int dt = 0; dt < 4; ++dt) {
                acc[dt] = __builtin_amdgcn_mfma_f32_16x16x32_bf16(vfs[dt][0], pf0, acc[dt], 0, 0, 0);
                acc[dt] = __builtin_amdgcn_mfma_f32_16x16x32_bf16(vfs[dt][1], pf1, acc[dt], 0, 0, 0);
            }
        }

        pbuf ^= 1;
    }

    const float inv = 1.f / lrun;
#pragma unroll
    for (int dt = 0; dt < 4; ++dt) {
#pragma unroll
        for (int r = 0; r < 4; r += 2) {
            uint_t pk = pack2bf(acc[dt][r] * inv, acc[dt][r + 1] * inv);
            *(uint_t*)(attout + (size_t)(t0 + lr) * DMODEL + h * HSZ + dt * 16 + lg * 4 + r) = pk;
        }
    }
}

// ---------------------------------------------------------------------------
extern "C" void kernel_launch(void* const* d_in, const int* in_sizes, int n_in,
                              void* d_out, int out_size, void* d_ws, size_t ws_size,
                              hipStream_t stream) {
    const int* idx = (const int*)d_in[0];
    const float* tok_emb = (const float*)d_in[1];
    const float* pos_emb = (const float*)d_in[2];
    const float* ln1_w = (const float*)d_in[3];
    const float* ln1_b = (const float*)d_in[4];
    const float* ln2_w = (const float*)d_in[5];
    const float* ln2_b = (const float*)d_in[6];
    const float* kqv_V = (const float*)d_in[7];
    const float* kqv_z = (const float*)d_in[8];
    const float* kqv_U = (const float*)d_in[9];
    const float* proj_V = (const float*)d_in[10];
    const float* proj_z = (const float*)d_in[11];
    const float* proj_U = (const float*)d_in[12];
    const float* f1_V = (const float*)d_in[13];
    const float* f1_z = (const float*)d_in[14];
    const float* f1_U = (const float*)d_in[15];
    const float* f2_V = (const float*)d_in[16];
    const float* f2_z = (const float*)d_in[17];
    const float* f2_U = (const float*)d_in[18];
    const float* lnf_w = (const float*)d_in[19];
    const float* lnf_b = (const float*)d_in[20];
    const float* lm_w = (const float*)d_in[21];

    // ---------------- workspace layout ----------------
    char* W = (char*)d_ws;
    float* x = (float*)W;                 W += (size_t)T_SEQ * DMODEL * 4;
    __hip_bfloat16* hbuf = (__hip_bfloat16*)W; W += (size_t)T_SEQ * DMODEL * 2;
    __hip_bfloat16* t1 = (__hip_bfloat16*)W;   W += (size_t)T_SEQ * NKQV * 2;
    __hip_bfloat16* qbuf = (__hip_bfloat16*)W; W += (size_t)NHEAD * T_SEQ * HSZ * 2;  // Q rows
    __hip_bfloat16* kb2 = (__hip_bfloat16*)W;  W += (size_t)NHEAD * T_SEQ * HSZ * 2;  // K chunk-tiled
    __hip_bfloat16* vt2 = (__hip_bfloat16*)W;  W += (size_t)NHEAD * HSZ * T_SEQ * 2;  // V^T chunk-tiled
    __hip_bfloat16* attb = (__hip_bfloat16*)W; W += (size_t)T_SEQ * DMODEL * 2;
    __hip_bfloat16* ffb = (__hip_bfloat16*)W;  W += (size_t)T_SEQ * FFDIM * 2;
    __hip_bfloat16* wkV = (__hip_bfloat16*)W;  W += (size_t)NLAYER * NKQV * DMODEL * 2;
    __hip_bfloat16* wkU = (__hip_bfloat16*)W;  W += (size_t)NLAYER * 3 * NHEAD * HSZ * RH * 2;
    __hip_bfloat16* wpV = (__hip_bfloat16*)W;  W += (size_t)NLAYER * RP * DMODEL * 2;
    __hip_bfloat16* wpU = (__hip_bfloat16*)W;  W += (size_t)NLAYER * DMODEL * RP * 2;
    __hip_bfloat16* w1V = (__hip_bfloat16*)W;  W += (size_t)NLAYER * RF * DMODEL * 2;
    __hip_bfloat16* w1U = (__hip_bfloat16*)W;  W += (size_t)NLAYER * FFDIM * RF * 2;
    __hip_bfloat16* w2V = (__hip_bfloat16*)W;  W += (size_t)NLAYER * RF * FFDIM * 2;
    __hip_bfloat16* w2U = (__hip_bfloat16*)W;  W += (size_t)NLAYER * DMODEL * RF * 2;
    __hip_bfloat16* wlm = (__hip_bfloat16*)W;  W += (size_t)VOCAB * DMODEL * 2;

    // batched weight conversion (one kernel)
    {
        CvtArgs a;
        a.s[0] = kqv_V;  a.d[0] = wkV;  a.n4[0] = (int)((size_t)NLAYER * NKQV * DMODEL / 4);
        a.s[1] = kqv_U;  a.d[1] = wkU;  a.n4[1] = (int)((size_t)NLAYER * 3 * NHEAD * HSZ * RH / 4);
        a.s[2] = proj_V; a.d[2] = wpV;  a.n4[2] = (int)((size_t)NLAYER * RP * DMODEL / 4);
        a.s[3] = proj_U; a.d[3] = wpU;  a.n4[3] = (int)((size_t)NLAYER * DMODEL * RP / 4);
        a.s[4] = f1_V;   a.d[4] = w1V;  a.n4[4] = (int)((size_t)NLAYER * RF * DMODEL / 4);
        a.s[5] = f1_U;   a.d[5] = w1U;  a.n4[5] = (int)((size_t)NLAYER * FFDIM * RF / 4);
        a.s[6] = f2_V;   a.d[6] = w2V;  a.n4[6] = (int)((size_t)NLAYER * RF * FFDIM / 4);
        a.s[7] = f2_U;   a.d[7] = w2U;  a.n4[7] = (int)((size_t)NLAYER * DMODEL * RF / 4);
        a.s[8] = lm_w;   a.d[8] = wlm;  a.n4[8] = (int)((size_t)VOCAB * DMODEL / 4);
        int total4 = 0;
        for (int k = 0; k < 9; ++k) total4 += a.n4[k];
        cvtall_k<<<dim3((total4 + 255) / 256), dim3(256), 0, stream>>>(a, total4);
    }

    embed_k<<<dim3(T_SEQ * DMODEL / 4 / 256), dim3(256), 0, stream>>>(idx, tok_emb, pos_emb, x);

    const int M = T_SEQ;
    for (int l = 0; l < NLAYER; ++l) {
        ln_k<<<dim3(T_SEQ), dim3(256), 0, stream>>>(x, ln1_w + l * DMODEL, ln1_b + l * DMODEL, hbuf);
        gemm1w<0><<<dim3((M / 64) * (NKQV / 64)), dim3(64), 0, stream>>>(
            hbuf, wkV + (size_t)l * NKQV * DMODEL, kqv_z + (size_t)l * NKQV,
            t1, nullptr, M, NKQV, DMODEL);
        kqv2_k<<<dim3(3 * NHEAD * T_SEQ * HSZ / 256), dim3(256), 0, stream>>>(
            t1, wkU + (size_t)l * 3 * NHEAD * HSZ * RH, qbuf, kb2, vt2);
        attn_k<<<dim3(T_SEQ / 64, NHEAD), dim3(256), 0, stream>>>(qbuf, kb2, vt2, attb);
        gemm1w<0><<<dim3((M / 64) * (RP / 64)), dim3(64), 0, stream>>>(
            attb, wpV + (size_t)l * RP * DMODEL, proj_z + (size_t)l * RP,
            t1, nullptr, M, RP, DMODEL);
        gemm1w<2><<<dim3((M / 64) * (DMODEL / 64)), dim3(64), 0, stream>>>(
            t1, wpU + (size_t)l * DMODEL * RP, nullptr,
            nullptr, x, M, DMODEL, RP);
        ln_k<<<dim3(T_SEQ), dim3(256), 0, stream>>>(x, ln2_w + l * DMODEL, ln2_b + l * DMODEL, hbuf);
        gemm1w<0><<<dim3((M / 64) * (RF / 64)), dim3(64), 0, stream>>>(
            hbuf, w1V + (size_t)l * RF * DMODEL, f1_z + (size_t)l * RF,
            t1, nullptr, M, RF, DMODEL);
        gemm1w<1><<<dim3((M / 64) * (FFDIM / 64)), dim3(64), 0, stream>>>(
            t1, w1U + (size_t)l * FFDIM * RF, nullptr,
            ffb, nullptr, M, FFDIM, RF);
        gemm1w<0><<<dim3((M / 64) * (RF / 64)), dim3(64), 0, stream>>>(
            ffb, w2V + (size_t)l * RF * FFDIM, f2_z + (size_t)l * RF,
            t1, nullptr, M, RF, FFDIM);
        gemm1w<2><<<dim3((M / 64) * (DMODEL / 64)), dim3(64), 0, stream>>>(
            t1, w2U + (size_t)l * DMODEL * RF, nullptr,
            nullptr, x, M, DMODEL, RF);
    }
    ln_k<<<dim3(T_SEQ), dim3(256), 0, stream>>>(x, lnf_w, lnf_b, hbuf);
    // logits: 256x256 counted-vmcnt pipeline, grid 8*125 = 1000 (div by 8)
    gemm256l<<<dim3((M / 256) * (VOCAB / 256)), dim3(512), 0, stream>>>(
        hbuf, wlm, (float*)d_out, M, VOCAB, DMODEL);
}

// Round 22
// 1015.519 us; speedup vs baseline: 1.0757x; 1.0757x over previous
//
#include <hip/hip_runtime.h>
#include <hip/hip_bf16.h>

// ---------------------------------------------------------------------------
// TransformerSquared forward on MI355X.
// R21 = exact R19 configuration (measured 1014.3us): gemm1w (1-wave,
// barrier-free, counted vmcnt) ONLY for K-deep V-GEMMs (kqvV, pV, f1V, f2V);
// U-GEMMs (K=256: too shallow for the 1-wave pipeline, R20 regression)
// back on gemm_t 64x64. Logits on gemm256l.
// ---------------------------------------------------------------------------

#define T_SEQ 2048
#define DMODEL 1024
#define NHEAD 16
#define HSZ 64
#define NLAYER 4
#define FFDIM 4096
#define RH 16
#define RP 256
#define RF 256
#define VOCAB 32000
#define NKQV (3 * NHEAD * RH) // 768

typedef short short8 __attribute__((ext_vector_type(8)));
typedef float f32x4 __attribute__((ext_vector_type(4)));
typedef unsigned int uint_t;
typedef unsigned short ushort_t;

__device__ __forceinline__ float bfbits2f(uint_t bits16_in_low) {
    uint_t b = bits16_in_low << 16;
    float f;
    __builtin_memcpy(&f, &b, 4);
    return f;
}
__device__ __forceinline__ ushort_t f2bfu(float f) {
    union { __hip_bfloat16 b; ushort_t u; } cv;
    cv.b = __float2bfloat16(f);
    return cv.u;
}
__device__ __forceinline__ uint_t pack2bf(float a, float b) {
    return (uint_t)f2bfu(a) | ((uint_t)f2bfu(b) << 16);
}

// async global->LDS, 16 bytes per lane. LDS dest = wave-uniform base + lane*16.
__device__ __forceinline__ void gld16(const __hip_bfloat16* g, short* l) {
    __builtin_amdgcn_global_load_lds(
        (const __attribute__((address_space(1))) void*)g,
        (__attribute__((address_space(3))) void*)l, 16, 0, 0);
}

// ----------------------- batched f32 -> bf16 convert -----------------------
struct CvtArgs {
    const float* s[9];
    __hip_bfloat16* d[9];
    int n4[9];
};
__global__ __launch_bounds__(256) void cvtall_k(CvtArgs a, int total4) {
    int i = blockIdx.x * 256 + threadIdx.x;
    if (i >= total4) return;
#pragma unroll
    for (int k = 0; k < 9; ++k) {
        if (i < a.n4[k]) {
            float4 v = ((const float4*)a.s[k])[i];
            ushort4 o;
            o.x = f2bfu(v.x); o.y = f2bfu(v.y); o.z = f2bfu(v.z); o.w = f2bfu(v.w);
            ((ushort4*)a.d[k])[i] = o;
            return;
        }
        i -= a.n4[k];
    }
}

// ------------------------------- embedding ---------------------------------
__global__ __launch_bounds__(256) void embed_k(const int* __restrict__ idx,
                                               const float* __restrict__ tok,
                                               const float* __restrict__ pos,
                                               float* __restrict__ x) {
    int i = blockIdx.x * 256 + threadIdx.x;          // over T*D/4
    int d4 = i & (DMODEL / 4 - 1);
    int t = i >> 8;                                   // D/4 = 256
    int tk = idx[t];
    float4 a = ((const float4*)(tok + (size_t)tk * DMODEL))[d4];
    float4 p = ((const float4*)(pos + (size_t)t * DMODEL))[d4];
    a.x += p.x; a.y += p.y; a.z += p.z; a.w += p.w;
    ((float4*)(x + (size_t)t * DMODEL))[d4] = a;
}

// ------------------------------- layernorm ---------------------------------
__global__ __launch_bounds__(256) void ln_k(const float* __restrict__ xin,
                                            const float* __restrict__ w,
                                            const float* __restrict__ b,
                                            __hip_bfloat16* __restrict__ out) {
    const int row = blockIdx.x, tid = threadIdx.x;
    const float4 v = ((const float4*)(xin + (size_t)row * DMODEL))[tid];
    float s = v.x + v.y + v.z + v.w;
    float q = v.x * v.x + v.y * v.y + v.z * v.z + v.w * v.w;
    for (int off = 32; off; off >>= 1) { s += __shfl_xor(s, off); q += __shfl_xor(q, off); }
    __shared__ float rs_[4], rq_[4];
    if ((tid & 63) == 0) { rs_[tid >> 6] = s; rq_[tid >> 6] = q; }
    __syncthreads();
    s = rs_[0] + rs_[1] + rs_[2] + rs_[3];
    q = rq_[0] + rq_[1] + rq_[2] + rq_[3];
    const float mean = s * (1.f / DMODEL);
    const float var = q * (1.f / DMODEL) - mean * mean;
    const float rstd = rsqrtf(var + 1e-5f);
    const float4 wv = ((const float4*)w)[tid];
    const float4 bv = ((const float4*)b)[tid];
    ushort4 o;
    o.x = f2bfu((v.x - mean) * rstd * wv.x + bv.x);
    o.y = f2bfu((v.y - mean) * rstd * wv.y + bv.y);
    o.z = f2bfu((v.z - mean) * rstd * wv.z + bv.z);
    o.w = f2bfu((v.w - mean) * rstd * wv.w + bv.w);
    ((ushort4*)out)[(size_t)row * (DMODEL / 4) + tid] = o;
}

// --------------------------- generic GEMM (A * B^T) ------------------------
// m97-structure, 2-barrier, both-sides XOR swizzle (verified 0 conflicts R4).
template <int BM, int BN, int MODE>
__global__ __launch_bounds__(256) void gemm_t(const __hip_bfloat16* __restrict__ A,
                                              const __hip_bfloat16* __restrict__ B,
                                              const float* __restrict__ colscale,
                                              __hip_bfloat16* __restrict__ Cb,
                                              float* __restrict__ Cf,
                                              int M, int N, int K) {
    constexpr int WM = (BN >= 128) ? 2 : 4;
    constexpr int WN = 4 / WM;
    constexpr int TM = BM / WM / 16;
    constexpr int TN = BN / WN / 16;
    constexpr int IA = BM / 32;     // gld16 iters for A tile
    constexpr int IB = BN / 32;
    __shared__ short As[BM * 64];
    __shared__ short Bs[BN * 64];
    const int tid = threadIdx.x;
    const int w = tid >> 6, ln = tid & 63, lr = ln & 15, lg = ln >> 4;
    const int GM = M / BM;

    const int nwg = gridDim.x;
    const int cpx = nwg >> 3;
    const int wg = (blockIdx.x & 7) * cpx + (blockIdx.x >> 3);
    const int bm = wg % GM, bn = wg / GM;
    const int wm = w / WN, wn = w % WN;

    f32x4 acc[TM][TN] = {};

    const int srow = tid >> 3;
    const int scol = (((tid & 7) ^ ((tid >> 3) & 7)) * 8);
    const __hip_bfloat16* Ag = A + (size_t)(bm * BM + srow) * K + scol;
    const __hip_bfloat16* Bg = B + (size_t)(bn * BN + srow) * K + scol;

    for (int kt = 0; kt < K; kt += 64) {
        __syncthreads();   // previous tile consumed
#pragma unroll
        for (int i = 0; i < IA; ++i)
            gld16(Ag + (size_t)(i * 32) * K + kt, &As[i * 2048 + w * 512]);
#pragma unroll
        for (int i = 0; i < IB; ++i)
            gld16(Bg + (size_t)(i * 32) * K + kt, &Bs[i * 2048 + w * 512]);
        __syncthreads();   // drains vmcnt + barrier

#pragma unroll
        for (int kk = 0; kk < 2; ++kk) {
            short8 af[TM], bf[TN];
#pragma unroll
            for (int m = 0; m < TM; ++m) {
                const int row = wm * (BM / WM) + m * 16 + lr;
                af[m] = *(const short8*)&As[row * 64 + (((kk * 4 + lg) ^ (lr & 7)) * 8)];
            }
#pragma unroll
            for (int n = 0; n < TN; ++n) {
                const int row = wn * (BN / WN) + n * 16 + lr;
                bf[n] = *(const short8*)&Bs[row * 64 + (((kk * 4 + lg) ^ (lr & 7)) * 8)];
            }
#pragma unroll
            for (int m = 0; m < TM; ++m)
#pragma unroll
                for (int n = 0; n < TN; ++n)
                    acc[m][n] = __builtin_amdgcn_mfma_f32_16x16x32_bf16(af[m], bf[n], acc[m][n], 0, 0, 0);
        }
    }

#pragma unroll
    for (int n = 0; n < TN; ++n) {
        const int col = bn * BN + wn * (BN / WN) + n * 16 + lr;
        float cs = 1.0f;
        if (MODE == 0 && colscale) cs = colscale[col];
#pragma unroll
        for (int m = 0; m < TM; ++m) {
#pragma unroll
            for (int rr = 0; rr < 4; ++rr) {
                const int row = bm * BM + wm * (BM / WM) + m * 16 + lg * 4 + rr;
                float v = acc[m][n][rr];
                const size_t o = (size_t)row * N + col;
                if (MODE == 0) {
                    Cb[o] = __float2bfloat16(v * cs);
                } else if (MODE == 1) {
                    v = 0.5f * v * (1.0f + erff(v * 0.70710678118654752f));
                    Cb[o] = __float2bfloat16(v);
                } else if (MODE == 2) {
                    Cf[o] += v;
                } else {
                    Cf[o] = v;
                }
            }
        }
    }
}

// ------------- 1-wave 64x64 GEMM, ring-2 counted vmcnt, no barriers --------
// For K-DEEP GEMMs only (K >= 1024: 16+ tiles amortize the prologue; R20
// showed K=256 regresses). Single wave => program-order s_waitcnt sync.
template <int MODE>
__global__ __launch_bounds__(64) void gemm1w(const __hip_bfloat16* __restrict__ A,
                                             const __hip_bfloat16* __restrict__ B,
                                             const float* __restrict__ colscale,
                                             __hip_bfloat16* __restrict__ Cb,
                                             float* __restrict__ Cf,
                                             int M, int N, int K) {
    __shared__ short As[2][64 * 64];
    __shared__ short Bs[2][64 * 64];
    const int tid = threadIdx.x;          // 0..63
    const int lr = tid & 15, lg = tid >> 4;
    const int GM = M / 64;

    const int nwg = gridDim.x;            // divisible by 8
    const int cpx = nwg >> 3;
    const int wg = (blockIdx.x & 7) * cpx + (blockIdx.x >> 3);
    const int bm = wg % GM, bn = wg / GM;

    const int srow = tid >> 3;            // 0..7
    const int scol = ((tid & 7) ^ srow) * 8;
    const __hip_bfloat16* Ag = A + (size_t)(bm * 64 + srow) * K + scol;
    const __hip_bfloat16* Bg = B + (size_t)(bn * 64 + srow) * K + scol;

    f32x4 acc[4][4] = {};

    auto STAGE = [&](int t) {
        const int b = t & 1;
        const size_t ko = (size_t)t * 64;
#pragma unroll
        for (int i = 0; i < 8; ++i) {
            gld16(Ag + (size_t)(i * 8) * K + ko, &As[b][i * 512]);
            gld16(Bg + (size_t)(i * 8) * K + ko, &Bs[b][i * 512]);
        }
    };

    STAGE(0); STAGE(1);                   // 32 outstanding

    const int T = K / 64;
    for (int t = 0; t < T; ++t) {
        if (t < T - 1) asm volatile("s_waitcnt vmcnt(16)" ::: "memory");
        else           asm volatile("s_waitcnt vmcnt(0)" ::: "memory");
        const short* Ab = As[t & 1];
        const short* Bb = Bs[t & 1];
        short8 af0[4], bf0[4], af1[4], bf1[4];
#pragma unroll
        for (int m = 0; m < 4; ++m) {
            const int R = m * 16 + lr;
            af0[m] = *(const short8*)&Ab[R * 64 + ((lg ^ (lr & 7)) * 8)];
            af1[m] = *(const short8*)&Ab[R * 64 + (((4 + lg) ^ (lr & 7)) * 8)];
            bf0[m] = *(const short8*)&Bb[R * 64 + ((lg ^ (lr & 7)) * 8)];
            bf1[m] = *(const short8*)&Bb[R * 64 + (((4 + lg) ^ (lr & 7)) * 8)];
        }
        asm volatile("s_waitcnt lgkmcnt(0)" ::: "memory");  // reads done
        if (t + 2 < T) STAGE(t + 2);       // safe: buffer fully consumed
        __builtin_amdgcn_sched_barrier(0);
#pragma unroll
        for (int m = 0; m < 4; ++m)
#pragma unroll
            for (int n = 0; n < 4; ++n)
                acc[m][n] = __builtin_amdgcn_mfma_f32_16x16x32_bf16(af0[m], bf0[n], acc[m][n], 0, 0, 0);
#pragma unroll
        for (int m = 0; m < 4; ++m)
#pragma unroll
            for (int n = 0; n < 4; ++n)
                acc[m][n] = __builtin_amdgcn_mfma_f32_16x16x32_bf16(af1[m], bf1[n], acc[m][n], 0, 0, 0);
    }

#pragma unroll
    for (int n = 0; n < 4; ++n) {
        const int col = bn * 64 + n * 16 + lr;
        float cs = 1.0f;
        if (MODE == 0 && colscale) cs = colscale[col];
#pragma unroll
        for (int m = 0; m < 4; ++m) {
#pragma unroll
            for (int rr = 0; rr < 4; ++rr) {
                const int row = bm * 64 + m * 16 + lg * 4 + rr;
                float v = acc[m][n][rr];
                const size_t o = (size_t)row * N + col;
                if (MODE == 0) {
                    Cb[o] = __float2bfloat16(v * cs);
                } else if (MODE == 1) {
                    v = 0.5f * v * (1.0f + erff(v * 0.70710678118654752f));
                    Cb[o] = __float2bfloat16(v);
                } else if (MODE == 2) {
                    Cf[o] += v;
                } else {
                    Cf[o] = v;
                }
            }
        }
    }
}

// ---------------- logits GEMM: 256x256, counted-vmcnt pipeline -------------
// (R12-verified: ~181us, MfmaUtil 31%, 0 conflicts — empirical best)
__global__ __launch_bounds__(512, 2) void gemm256l(const __hip_bfloat16* __restrict__ A,
                                                   const __hip_bfloat16* __restrict__ B,
                                                   float* __restrict__ C,
                                                   int M, int N, int K) {
    __shared__ short As[2][256 * 64];
    __shared__ short Bs[2][256 * 64];
    const int tid = threadIdx.x;
    const int w = tid >> 6, ln = tid & 63, lr = ln & 15, lg = ln >> 4;
    const int wm = w >> 2, wn = w & 3;
    const int GM = M / 256;              // 8

    const int nwg = gridDim.x;           // 1000
    const int cpx = nwg >> 3;            // 125
    const int wg = (blockIdx.x & 7) * cpx + (blockIdx.x >> 3);
    const int bm = wg % GM, bn = wg / GM;

    const int srow = tid >> 3;           // 0..63
    const int scol = (((tid & 7) ^ ((tid >> 3) & 7)) * 8);
    const __hip_bfloat16* Ag = A + (size_t)(bm * 256 + srow) * K + scol;
    const __hip_bfloat16* Bg = B + (size_t)(bn * 256 + srow) * K + scol;
    const int ldsb = w * 512;            // shorts; wave-uniform

    f32x4 acc[8][4] = {};

    auto STAGE = [&](int t) {
        const int b = t & 1;
        const size_t ko = (size_t)t * 64;
#pragma unroll
        for (int i = 0; i < 4; ++i) {
            gld16(Ag + (size_t)(i * 64) * K + ko, &As[b][i * 4096 + ldsb]);
            gld16(Bg + (size_t)(i * 64) * K + ko, &Bs[b][i * 4096 + ldsb]);
        }
    };

    STAGE(0); STAGE(1);                   // 16 vmem / wave outstanding

    const int T = K / 64;                 // 16
    for (int t = 0; t < T; ++t) {
        if (t < T - 1) asm volatile("s_waitcnt vmcnt(8)" ::: "memory");
        else           asm volatile("s_waitcnt vmcnt(0)" ::: "memory");
        __builtin_amdgcn_s_barrier();     // tile t present in buf[t&1]

        const short* Ab = As[t & 1];
        const short* Bb = Bs[t & 1];
        short8 af0[8], bf0[4], af1[8], bf1[4];
#pragma unroll
        for (int m = 0; m < 8; ++m) {
            const int R = wm * 128 + m * 16 + lr;
            af0[m] = *(const short8*)&Ab[R * 64 + ((lg ^ (lr & 7)) * 8)];
        }
#pragma unroll
        for (int n = 0; n < 4; ++n) {
            const int R = wn * 64 + n * 16 + lr;
            bf0[n] = *(const short8*)&Bb[R * 64 + ((lg ^ (lr & 7)) * 8)];
        }
        // kk0 MFMAs (compiler may overlap kk1 reads below with these)
#pragma unroll
        for (int m = 0; m < 8; ++m)
#pragma unroll
            for (int n = 0; n < 4; ++n)
                acc[m][n] = __builtin_amdgcn_mfma_f32_16x16x32_bf16(af0[m], bf0[n], acc[m][n], 0, 0, 0);
#pragma unroll
        for (int m = 0; m < 8; ++m) {
            const int R = wm * 128 + m * 16 + lr;
            af1[m] = *(const short8*)&Ab[R * 64 + (((4 + lg) ^ (lr & 7)) * 8)];
        }
#pragma unroll
        for (int n = 0; n < 4; ++n) {
            const int R = wn * 64 + n * 16 + lr;
            bf1[n] = *(const short8*)&Bb[R * 64 + (((4 + lg) ^ (lr & 7)) * 8)];
        }
        asm volatile("s_waitcnt lgkmcnt(0)" ::: "memory");
        __builtin_amdgcn_s_barrier();     // all waves done reading buf[t&1]
        if (t + 2 < T) STAGE(t + 2);      // overwrite buf[t&1] (safe)
        __builtin_amdgcn_sched_barrier(0);
        __builtin_amdgcn_s_setprio(1);
#pragma unroll
        for (int m = 0; m < 8; ++m)
#pragma unroll
            for (int n = 0; n < 4; ++n)
                acc[m][n] = __builtin_amdgcn_mfma_f32_16x16x32_bf16(af1[m], bf1[n], acc[m][n], 0, 0, 0);
        __builtin_amdgcn_s_setprio(0);
    }

#pragma unroll
    for (int m = 0; m < 8; ++m) {
        const int row = bm * 256 + wm * 128 + m * 16 + lg * 4;
#pragma unroll
        for (int rr = 0; rr < 4; ++rr) {
            float* crow = C + (size_t)(row + rr) * N + bn * 256 + wn * 64 + lr;
#pragma unroll
            for (int n = 0; n < 4; ++n)
                crow[n * 16] = acc[m][n][rr];
        }
    }
}

// ------------- per-head SVF U-projection (K=16) + layout fusion ------------
__global__ __launch_bounds__(256) void kqv2_k(const __hip_bfloat16* __restrict__ t1,
                                              const __hip_bfloat16* __restrict__ U,
                                              __hip_bfloat16* __restrict__ qb,
                                              __hip_bfloat16* __restrict__ kb2,
                                              __hip_bfloat16* __restrict__ vt2) {
    size_t i = (size_t)blockIdx.x * 256 + threadIdx.x; // 3*16*2048*64
    int s = (int)(i & 63);
    size_t rest = i >> 6;
    int t = (int)(rest & (T_SEQ - 1));
    int gh = (int)(rest >> 11);                        // 0..47, g-major
    const short8* trow = (const short8*)(t1 + (size_t)t * NKQV + gh * RH);
    const short8* urow = (const short8*)(U + ((size_t)gh * HSZ + s) * RH);
    short8 ta = trow[0], tb = trow[1];
    short8 ua = urow[0], ub = urow[1];
    float acc = 0.f;
#pragma unroll
    for (int j = 0; j < 8; ++j) {
        acc += bfbits2f((ushort_t)ta[j]) * bfbits2f((ushort_t)ua[j]);
        acc += bfbits2f((ushort_t)tb[j]) * bfbits2f((ushort_t)ub[j]);
    }
    const ushort_t val = f2bfu(acc);
    const int g = gh >> 4, h = gh & 15;               // block-uniform g
    if (g == 1) {
        ((ushort_t*)qb)[((size_t)h * T_SEQ + t) * HSZ + s] = val;
    } else if (g == 0) {
        const int tile = t >> 6, gg = (t >> 4) & 3, lr = t & 15;
        const int half = s >> 5, lg = (s >> 3) & 3, j = s & 7;
        const int c = gg * 2 + half, ln = lg * 16 + lr;
        ((ushort_t*)kb2)[(((size_t)h * 32 + tile) * 8 + c) * 512 + ln * 8 + j] = val;
    } else {
        const int tile = t >> 6, half = (t >> 5) & 1, lg2 = (t >> 3) & 3, j2 = t & 7;
        const int dt = s >> 4, lr2 = s & 15;
        const int c = dt * 2 + half, ln = lg2 * 16 + lr2;
        ((ushort_t*)vt2)[(((size_t)h * 32 + tile) * 8 + c) * 512 + ln * 8 + j2] = val;
    }
}

// --------------------------- MFMA flash attention --------------------------
// KVBLK=128 (two chunk-tiles per softmax round). Masked-tail pair +
// defer-max (T13).
__global__ __launch_bounds__(256) void attn_k(const __hip_bfloat16* __restrict__ qb,
                                              const __hip_bfloat16* __restrict__ kb2,
                                              const __hip_bfloat16* __restrict__ vt2,
                                              __hip_bfloat16* __restrict__ attout) {
    __shared__ short P_s[2][4][16 * 136];  // [dbuf][wave][16 q x 128 u], stride 136
    const int tid = threadIdx.x, w = tid >> 6, ln = tid & 63;
    const int lr = ln & 15, lg = ln >> 4;
    const int f = blockIdx.y * 32 + blockIdx.x;
    const int h = ((f & 7) << 1) | ((f >> 3) & 1);
    const int bi = f >> 4;
    const int t0 = bi * 16 + w * 512;
    const size_t hb = (size_t)h * T_SEQ;
    const size_t hB = (size_t)h * 32;   // tile base for chunk addressing
    const float SCL = 0.18033688011112042f; // 0.125 * log2(e)

    short8 qf0 = *(const short8*)(qb + (hb + t0 + lr) * HSZ + lg * 8);
    short8 qf1 = *(const short8*)(qb + (hb + t0 + lr) * HSZ + 32 + lg * 8);

    f32x4 acc[4] = {};
    float mrun = -3e38f, lrun = 0.f;
    int pbuf = 0;

    short8 kf[8][2];
#pragma unroll
    for (int c = 0; c < 8; ++c) {
        kf[c][0] = *(const short8*)(kb2 + ((hB + (c >> 2)) * 8 + (c & 3) * 2 + 0) * 512 + (size_t)ln * 8);
        kf[c][1] = *(const short8*)(kb2 + ((hB + (c >> 2)) * 8 + (c & 3) * 2 + 1) * 512 + (size_t)ln * 8);
    }

    const int last = t0 >> 7;             // index of the final 128-pair
    for (int it2 = 0; it2 <= last; ++it2) {
        f32x4 st[8];
#pragma unroll
        for (int c = 0; c < 8; ++c) {
            f32x4 z = {};
            z = __builtin_amdgcn_mfma_f32_16x16x32_bf16(kf[c][0], qf0, z, 0, 0, 0);
            st[c] = __builtin_amdgcn_mfma_f32_16x16x32_bf16(kf[c][1], qf1, z, 0, 0, 0);
        }

        if (it2 < last) {                 // prefetch next pair
            const int tn = (it2 + 1) * 2;
#pragma unroll
            for (int c = 0; c < 8; ++c) {
                kf[c][0] = *(const short8*)(kb2 + ((hB + tn + (c >> 2)) * 8 + (c & 3) * 2 + 0) * 512 + (size_t)ln * 8);
                kf[c][1] = *(const short8*)(kb2 + ((hB + tn + (c >> 2)) * 8 + (c & 3) * 2 + 1) * 512 + (size_t)ln * 8);
            }
        }

        float sv[32];
        if (it2 == last) {                // only the final pair needs masking
            const int u0 = it2 * 128;
            const int qg = t0 + lr;
#pragma unroll
            for (int c = 0; c < 8; ++c)
#pragma unroll
                for (int r = 0; r < 4; ++r) {
                    float v = st[c][r] * SCL;
                    if (u0 + c * 16 + lg * 4 + r > qg) v = -1e30f;
                    sv[c * 4 + r] = v;
                }
        } else {
#pragma unroll
            for (int c = 0; c < 8; ++c)
#pragma unroll
                for (int r = 0; r < 4; ++r)
                    sv[c * 4 + r] = st[c][r] * SCL;
        }

        float mm[8];
#pragma unroll
        for (int c = 0; c < 8; ++c)
            mm[c] = fmaxf(fmaxf(sv[c * 4], sv[c * 4 + 1]), fmaxf(sv[c * 4 + 2], sv[c * 4 + 3]));
        float tm = fmaxf(fmaxf(fmaxf(mm[0], mm[1]), fmaxf(mm[2], mm[3])),
                         fmaxf(fmaxf(mm[4], mm[5]), fmaxf(mm[6], mm[7])));
        tm = fmaxf(tm, __shfl_xor(tm, 16));
        tm = fmaxf(tm, __shfl_xor(tm, 32));

        if (!__all(tm - mrun <= 8.0f)) {  // defer-max (T13)
            const float mnew = fmaxf(mrun, tm);
            const float corr = exp2f(mrun - mnew);
            lrun *= corr;
#pragma unroll
            for (int dt = 0; dt < 4; ++dt) acc[dt] *= corr;
            mrun = mnew;
        }

        float pv[32];
        float ls = 0.f;
#pragma unroll
        for (int j = 0; j < 32; ++j) { pv[j] = exp2f(sv[j] - mrun); ls += pv[j]; }
        ls += __shfl_xor(ls, 16);
        ls += __shfl_xor(ls, 32);
        lrun += ls;

        uint_t* pw = (uint_t*)P_s[pbuf][w];
        const int wb = lr * 68 + lg * 2;
#pragma unroll
        for (int c = 0; c < 8; ++c) {
            pw[wb + c * 8 + 0] = pack2bf(pv[c * 4 + 0], pv[c * 4 + 1]);
            pw[wb + c * 8 + 1] = pack2bf(pv[c * 4 + 2], pv[c * 4 + 3]);
        }
        asm volatile("s_waitcnt lgkmcnt(0)" ::: "memory");

#pragma unroll
        for (int s = 0; s < 2; ++s) {
            short8 vfs[4][2];
#pragma unroll
            for (int dt = 0; dt < 4; ++dt) {
                vfs[dt][0] = *(const short8*)(vt2 + ((hB + it2 * 2 + s) * 8 + dt * 2 + 0) * 512 + (size_t)ln * 8);
                vfs[dt][1] = *(const short8*)(vt2 + ((hB + it2 * 2 + s) * 8 + dt * 2 + 1) * 512 + (size_t)ln * 8);
            }
            short8 pf0 = *(const short8*)(&P_s[pbuf][w][lr * 136 + s * 64 + lg * 8]);
            short8 pf1 = *(const short8*)(&P_s[pbuf][w][lr * 136 + s * 64 + 32 + lg * 8]);
#pragma unroll
            for (int dt = 0; dt < 4; ++dt) {
                acc[dt] = __builtin_amdgcn_mfma_f32_16x16x32_bf16(vfs[dt][0], pf0, acc[dt], 0, 0, 0);
                acc[dt] = __builtin_amdgcn_mfma_f32_16x16x32_bf16(vfs[dt][1], pf1, acc[dt], 0, 0, 0);
            }
        }

        pbuf ^= 1;
    }

    const float inv = 1.f / lrun;
#pragma unroll
    for (int dt = 0; dt < 4; ++dt) {
#pragma unroll
        for (int r = 0; r < 4; r += 2) {
            uint_t pk = pack2bf(acc[dt][r] * inv, acc[dt][r + 1] * inv);
            *(uint_t*)(attout + (size_t)(t0 + lr) * DMODEL + h * HSZ + dt * 16 + lg * 4 + r) = pk;
        }
    }
}

// ---------------------------------------------------------------------------
extern "C" void kernel_launch(void* const* d_in, const int* in_sizes, int n_in,
                              void* d_out, int out_size, void* d_ws, size_t ws_size,
                              hipStream_t stream) {
    const int* idx = (const int*)d_in[0];
    const float* tok_emb = (const float*)d_in[1];
    const float* pos_emb = (const float*)d_in[2];
    const float* ln1_w = (const float*)d_in[3];
    const float* ln1_b = (const float*)d_in[4];
    const float* ln2_w = (const float*)d_in[5];
    const float* ln2_b = (const float*)d_in[6];
    const float* kqv_V = (const float*)d_in[7];
    const float* kqv_z = (const float*)d_in[8];
    const float* kqv_U = (const float*)d_in[9];
    const float* proj_V = (const float*)d_in[10];
    const float* proj_z = (const float*)d_in[11];
    const float* proj_U = (const float*)d_in[12];
    const float* f1_V = (const float*)d_in[13];
    const float* f1_z = (const float*)d_in[14];
    const float* f1_U = (const float*)d_in[15];
    const float* f2_V = (const float*)d_in[16];
    const float* f2_z = (const float*)d_in[17];
    const float* f2_U = (const float*)d_in[18];
    const float* lnf_w = (const float*)d_in[19];
    const float* lnf_b = (const float*)d_in[20];
    const float* lm_w = (const float*)d_in[21];

    // ---------------- workspace layout ----------------
    char* W = (char*)d_ws;
    float* x = (float*)W;                 W += (size_t)T_SEQ * DMODEL * 4;
    __hip_bfloat16* hbuf = (__hip_bfloat16*)W; W += (size_t)T_SEQ * DMODEL * 2;
    __hip_bfloat16* t1 = (__hip_bfloat16*)W;   W += (size_t)T_SEQ * NKQV * 2;
    __hip_bfloat16* qbuf = (__hip_bfloat16*)W; W += (size_t)NHEAD * T_SEQ * HSZ * 2;  // Q rows
    __hip_bfloat16* kb2 = (__hip_bfloat16*)W;  W += (size_t)NHEAD * T_SEQ * HSZ * 2;  // K chunk-tiled
    __hip_bfloat16* vt2 = (__hip_bfloat16*)W;  W += (size_t)NHEAD * HSZ * T_SEQ * 2;  // V^T chunk-tiled
    __hip_bfloat16* attb = (__hip_bfloat16*)W; W += (size_t)T_SEQ * DMODEL * 2;
    __hip_bfloat16* ffb = (__hip_bfloat16*)W;  W += (size_t)T_SEQ * FFDIM * 2;
    __hip_bfloat16* wkV = (__hip_bfloat16*)W;  W += (size_t)NLAYER * NKQV * DMODEL * 2;
    __hip_bfloat16* wkU = (__hip_bfloat16*)W;  W += (size_t)NLAYER * 3 * NHEAD * HSZ * RH * 2;
    __hip_bfloat16* wpV = (__hip_bfloat16*)W;  W += (size_t)NLAYER * RP * DMODEL * 2;
    __hip_bfloat16* wpU = (__hip_bfloat16*)W;  W += (size_t)NLAYER * DMODEL * RP * 2;
    __hip_bfloat16* w1V = (__hip_bfloat16*)W;  W += (size_t)NLAYER * RF * DMODEL * 2;
    __hip_bfloat16* w1U = (__hip_bfloat16*)W;  W += (size_t)NLAYER * FFDIM * RF * 2;
    __hip_bfloat16* w2V = (__hip_bfloat16*)W;  W += (size_t)NLAYER * RF * FFDIM * 2;
    __hip_bfloat16* w2U = (__hip_bfloat16*)W;  W += (size_t)NLAYER * DMODEL * RF * 2;
    __hip_bfloat16* wlm = (__hip_bfloat16*)W;  W += (size_t)VOCAB * DMODEL * 2;

    // batched weight conversion (one kernel)
    {
        CvtArgs a;
        a.s[0] = kqv_V;  a.d[0] = wkV;  a.n4[0] = (int)((size_t)NLAYER * NKQV * DMODEL / 4);
        a.s[1] = kqv_U;  a.d[1] = wkU;  a.n4[1] = (int)((size_t)NLAYER * 3 * NHEAD * HSZ * RH / 4);
        a.s[2] = proj_V; a.d[2] = wpV;  a.n4[2] = (int)((size_t)NLAYER * RP * DMODEL / 4);
        a.s[3] = proj_U; a.d[3] = wpU;  a.n4[3] = (int)((size_t)NLAYER * DMODEL * RP / 4);
        a.s[4] = f1_V;   a.d[4] = w1V;  a.n4[4] = (int)((size_t)NLAYER * RF * DMODEL / 4);
        a.s[5] = f1_U;   a.d[5] = w1U;  a.n4[5] = (int)((size_t)NLAYER * FFDIM * RF / 4);
        a.s[6] = f2_V;   a.d[6] = w2V;  a.n4[6] = (int)((size_t)NLAYER * RF * FFDIM / 4);
        a.s[7] = f2_U;   a.d[7] = w2U;  a.n4[7] = (int)((size_t)NLAYER * DMODEL * RF / 4);
        a.s[8] = lm_w;   a.d[8] = wlm;  a.n4[8] = (int)((size_t)VOCAB * DMODEL / 4);
        int total4 = 0;
        for (int k = 0; k < 9; ++k) total4 += a.n4[k];
        cvtall_k<<<dim3((total4 + 255) / 256), dim3(256), 0, stream>>>(a, total4);
    }

    embed_k<<<dim3(T_SEQ * DMODEL / 4 / 256), dim3(256), 0, stream>>>(idx, tok_emb, pos_emb, x);

    const int M = T_SEQ;
    for (int l = 0; l < NLAYER; ++l) {
        ln_k<<<dim3(T_SEQ), dim3(256), 0, stream>>>(x, ln1_w + l * DMODEL, ln1_b + l * DMODEL, hbuf);
        gemm1w<0><<<dim3((M / 64) * (NKQV / 64)), dim3(64), 0, stream>>>(
            hbuf, wkV + (size_t)l * NKQV * DMODEL, kqv_z + (size_t)l * NKQV,
            t1, nullptr, M, NKQV, DMODEL);
        kqv2_k<<<dim3(3 * NHEAD * T_SEQ * HSZ / 256), dim3(256), 0, stream>>>(
            t1, wkU + (size_t)l * 3 * NHEAD * HSZ * RH, qbuf, kb2, vt2);
        attn_k<<<dim3(T_SEQ / 64, NHEAD), dim3(256), 0, stream>>>(qbuf, kb2, vt2, attb);
        gemm1w<0><<<dim3((M / 64) * (RP / 64)), dim3(64), 0, stream>>>(
            attb, wpV + (size_t)l * RP * DMODEL, proj_z + (size_t)l * RP,
            t1, nullptr, M, RP, DMODEL);
        gemm_t<64, 64, 2><<<dim3((M / 64) * (DMODEL / 64)), dim3(256), 0, stream>>>(
            t1, wpU + (size_t)l * DMODEL * RP, nullptr,
            nullptr, x, M, DMODEL, RP);
        ln_k<<<dim3(T_SEQ), dim3(256), 0, stream>>>(x, ln2_w + l * DMODEL, ln2_b + l * DMODEL, hbuf);
        gemm1w<0><<<dim3((M / 64) * (RF / 64)), dim3(64), 0, stream>>>(
            hbuf, w1V + (size_t)l * RF * DMODEL, f1_z + (size_t)l * RF,
            t1, nullptr, M, RF, DMODEL);
        gemm_t<64, 64, 1><<<dim3((M / 64) * (FFDIM / 64)), dim3(256), 0, stream>>>(
            t1, w1U + (size_t)l * FFDIM * RF, nullptr,
            ffb, nullptr, M, FFDIM, RF);
        gemm1w<0><<<dim3((M / 64) * (RF / 64)), dim3(64), 0, stream>>>(
            ffb, w2V + (size_t)l * RF * FFDIM, f2_z + (size_t)l * RF,
            t1, nullptr, M, RF, FFDIM);
        gemm_t<64, 64, 2><<<dim3((M / 64) * (DMODEL / 64)), dim3(256), 0, stream>>>(
            t1, w2U + (size_t)l * DMODEL * RF, nullptr,
            nullptr, x, M, DMODEL, RF);
    }
    ln_k<<<dim3(T_SEQ), dim3(256), 0, stream>>>(x, lnf_w, lnf_b, hbuf);
    // logits: 256x256 counted-vmcnt pipeline, grid 8*125 = 1000 (div by 8)
    gemm256l<<<dim3((M / 256) * (VOCAB / 256)), dim3(512), 0, stream>>>(
        hbuf, wlm, (float*)d_out, M, VOCAB, DMODEL);
}

// Round 23
// 1012.931 us; speedup vs baseline: 1.0784x; 1.0026x over previous
//
#include <hip/hip_runtime.h>
#include <hip/hip_bf16.h>

// ---------------------------------------------------------------------------
// TransformerSquared forward on MI355X.
// R22 = R21 base (1015us); attn_k V-fragment loads hoisted above the softmax
// chain (they were pinned below the P-store lgkmcnt "memory" clobber), so
// their L2 latency overlaps softmax VALU instead of stalling the PV phase.
// ---------------------------------------------------------------------------

#define T_SEQ 2048
#define DMODEL 1024
#define NHEAD 16
#define HSZ 64
#define NLAYER 4
#define FFDIM 4096
#define RH 16
#define RP 256
#define RF 256
#define VOCAB 32000
#define NKQV (3 * NHEAD * RH) // 768

typedef short short8 __attribute__((ext_vector_type(8)));
typedef float f32x4 __attribute__((ext_vector_type(4)));
typedef unsigned int uint_t;
typedef unsigned short ushort_t;

__device__ __forceinline__ float bfbits2f(uint_t bits16_in_low) {
    uint_t b = bits16_in_low << 16;
    float f;
    __builtin_memcpy(&f, &b, 4);
    return f;
}
__device__ __forceinline__ ushort_t f2bfu(float f) {
    union { __hip_bfloat16 b; ushort_t u; } cv;
    cv.b = __float2bfloat16(f);
    return cv.u;
}
__device__ __forceinline__ uint_t pack2bf(float a, float b) {
    return (uint_t)f2bfu(a) | ((uint_t)f2bfu(b) << 16);
}

// async global->LDS, 16 bytes per lane. LDS dest = wave-uniform base + lane*16.
__device__ __forceinline__ void gld16(const __hip_bfloat16* g, short* l) {
    __builtin_amdgcn_global_load_lds(
        (const __attribute__((address_space(1))) void*)g,
        (__attribute__((address_space(3))) void*)l, 16, 0, 0);
}

// ----------------------- batched f32 -> bf16 convert -----------------------
struct CvtArgs {
    const float* s[9];
    __hip_bfloat16* d[9];
    int n4[9];
};
__global__ __launch_bounds__(256) void cvtall_k(CvtArgs a, int total4) {
    int i = blockIdx.x * 256 + threadIdx.x;
    if (i >= total4) return;
#pragma unroll
    for (int k = 0; k < 9; ++k) {
        if (i < a.n4[k]) {
            float4 v = ((const float4*)a.s[k])[i];
            ushort4 o;
            o.x = f2bfu(v.x); o.y = f2bfu(v.y); o.z = f2bfu(v.z); o.w = f2bfu(v.w);
            ((ushort4*)a.d[k])[i] = o;
            return;
        }
        i -= a.n4[k];
    }
}

// ------------------------------- embedding ---------------------------------
__global__ __launch_bounds__(256) void embed_k(const int* __restrict__ idx,
                                               const float* __restrict__ tok,
                                               const float* __restrict__ pos,
                                               float* __restrict__ x) {
    int i = blockIdx.x * 256 + threadIdx.x;          // over T*D/4
    int d4 = i & (DMODEL / 4 - 1);
    int t = i >> 8;                                   // D/4 = 256
    int tk = idx[t];
    float4 a = ((const float4*)(tok + (size_t)tk * DMODEL))[d4];
    float4 p = ((const float4*)(pos + (size_t)t * DMODEL))[d4];
    a.x += p.x; a.y += p.y; a.z += p.z; a.w += p.w;
    ((float4*)(x + (size_t)t * DMODEL))[d4] = a;
}

// ------------------------------- layernorm ---------------------------------
__global__ __launch_bounds__(256) void ln_k(const float* __restrict__ xin,
                                            const float* __restrict__ w,
                                            const float* __restrict__ b,
                                            __hip_bfloat16* __restrict__ out) {
    const int row = blockIdx.x, tid = threadIdx.x;
    const float4 v = ((const float4*)(xin + (size_t)row * DMODEL))[tid];
    float s = v.x + v.y + v.z + v.w;
    float q = v.x * v.x + v.y * v.y + v.z * v.z + v.w * v.w;
    for (int off = 32; off; off >>= 1) { s += __shfl_xor(s, off); q += __shfl_xor(q, off); }
    __shared__ float rs_[4], rq_[4];
    if ((tid & 63) == 0) { rs_[tid >> 6] = s; rq_[tid >> 6] = q; }
    __syncthreads();
    s = rs_[0] + rs_[1] + rs_[2] + rs_[3];
    q = rq_[0] + rq_[1] + rq_[2] + rq_[3];
    const float mean = s * (1.f / DMODEL);
    const float var = q * (1.f / DMODEL) - mean * mean;
    const float rstd = rsqrtf(var + 1e-5f);
    const float4 wv = ((const float4*)w)[tid];
    const float4 bv = ((const float4*)b)[tid];
    ushort4 o;
    o.x = f2bfu((v.x - mean) * rstd * wv.x + bv.x);
    o.y = f2bfu((v.y - mean) * rstd * wv.y + bv.y);
    o.z = f2bfu((v.z - mean) * rstd * wv.z + bv.z);
    o.w = f2bfu((v.w - mean) * rstd * wv.w + bv.w);
    ((ushort4*)out)[(size_t)row * (DMODEL / 4) + tid] = o;
}

// --------------------------- generic GEMM (A * B^T) ------------------------
// m97-structure, 2-barrier, both-sides XOR swizzle (verified 0 conflicts R4).
template <int BM, int BN, int MODE>
__global__ __launch_bounds__(256) void gemm_t(const __hip_bfloat16* __restrict__ A,
                                              const __hip_bfloat16* __restrict__ B,
                                              const float* __restrict__ colscale,
                                              __hip_bfloat16* __restrict__ Cb,
                                              float* __restrict__ Cf,
                                              int M, int N, int K) {
    constexpr int WM = (BN >= 128) ? 2 : 4;
    constexpr int WN = 4 / WM;
    constexpr int TM = BM / WM / 16;
    constexpr int TN = BN / WN / 16;
    constexpr int IA = BM / 32;     // gld16 iters for A tile
    constexpr int IB = BN / 32;
    __shared__ short As[BM * 64];
    __shared__ short Bs[BN * 64];
    const int tid = threadIdx.x;
    const int w = tid >> 6, ln = tid & 63, lr = ln & 15, lg = ln >> 4;
    const int GM = M / BM;

    const int nwg = gridDim.x;
    const int cpx = nwg >> 3;
    const int wg = (blockIdx.x & 7) * cpx + (blockIdx.x >> 3);
    const int bm = wg % GM, bn = wg / GM;
    const int wm = w / WN, wn = w % WN;

    f32x4 acc[TM][TN] = {};

    const int srow = tid >> 3;
    const int scol = (((tid & 7) ^ ((tid >> 3) & 7)) * 8);
    const __hip_bfloat16* Ag = A + (size_t)(bm * BM + srow) * K + scol;
    const __hip_bfloat16* Bg = B + (size_t)(bn * BN + srow) * K + scol;

    for (int kt = 0; kt < K; kt += 64) {
        __syncthreads();   // previous tile consumed
#pragma unroll
        for (int i = 0; i < IA; ++i)
            gld16(Ag + (size_t)(i * 32) * K + kt, &As[i * 2048 + w * 512]);
#pragma unroll
        for (int i = 0; i < IB; ++i)
            gld16(Bg + (size_t)(i * 32) * K + kt, &Bs[i * 2048 + w * 512]);
        __syncthreads();   // drains vmcnt + barrier

#pragma unroll
        for (int kk = 0; kk < 2; ++kk) {
            short8 af[TM], bf[TN];
#pragma unroll
            for (int m = 0; m < TM; ++m) {
                const int row = wm * (BM / WM) + m * 16 + lr;
                af[m] = *(const short8*)&As[row * 64 + (((kk * 4 + lg) ^ (lr & 7)) * 8)];
            }
#pragma unroll
            for (int n = 0; n < TN; ++n) {
                const int row = wn * (BN / WN) + n * 16 + lr;
                bf[n] = *(const short8*)&Bs[row * 64 + (((kk * 4 + lg) ^ (lr & 7)) * 8)];
            }
#pragma unroll
            for (int m = 0; m < TM; ++m)
#pragma unroll
                for (int n = 0; n < TN; ++n)
                    acc[m][n] = __builtin_amdgcn_mfma_f32_16x16x32_bf16(af[m], bf[n], acc[m][n], 0, 0, 0);
        }
    }

#pragma unroll
    for (int n = 0; n < TN; ++n) {
        const int col = bn * BN + wn * (BN / WN) + n * 16 + lr;
        float cs = 1.0f;
        if (MODE == 0 && colscale) cs = colscale[col];
#pragma unroll
        for (int m = 0; m < TM; ++m) {
#pragma unroll
            for (int rr = 0; rr < 4; ++rr) {
                const int row = bm * BM + wm * (BM / WM) + m * 16 + lg * 4 + rr;
                float v = acc[m][n][rr];
                const size_t o = (size_t)row * N + col;
                if (MODE == 0) {
                    Cb[o] = __float2bfloat16(v * cs);
                } else if (MODE == 1) {
                    v = 0.5f * v * (1.0f + erff(v * 0.70710678118654752f));
                    Cb[o] = __float2bfloat16(v);
                } else if (MODE == 2) {
                    Cf[o] += v;
                } else {
                    Cf[o] = v;
                }
            }
        }
    }
}

// ------------- 1-wave 64x64 GEMM, ring-2 counted vmcnt, no barriers --------
// For K-DEEP GEMMs only (K >= 1024; R20 showed K=256 regresses).
template <int MODE>
__global__ __launch_bounds__(64) void gemm1w(const __hip_bfloat16* __restrict__ A,
                                             const __hip_bfloat16* __restrict__ B,
                                             const float* __restrict__ colscale,
                                             __hip_bfloat16* __restrict__ Cb,
                                             float* __restrict__ Cf,
                                             int M, int N, int K) {
    __shared__ short As[2][64 * 64];
    __shared__ short Bs[2][64 * 64];
    const int tid = threadIdx.x;          // 0..63
    const int lr = tid & 15, lg = tid >> 4;
    const int GM = M / 64;

    const int nwg = gridDim.x;            // divisible by 8
    const int cpx = nwg >> 3;
    const int wg = (blockIdx.x & 7) * cpx + (blockIdx.x >> 3);
    const int bm = wg % GM, bn = wg / GM;

    const int srow = tid >> 3;            // 0..7
    const int scol = ((tid & 7) ^ srow) * 8;
    const __hip_bfloat16* Ag = A + (size_t)(bm * 64 + srow) * K + scol;
    const __hip_bfloat16* Bg = B + (size_t)(bn * 64 + srow) * K + scol;

    f32x4 acc[4][4] = {};

    auto STAGE = [&](int t) {
        const int b = t & 1;
        const size_t ko = (size_t)t * 64;
#pragma unroll
        for (int i = 0; i < 8; ++i) {
            gld16(Ag + (size_t)(i * 8) * K + ko, &As[b][i * 512]);
            gld16(Bg + (size_t)(i * 8) * K + ko, &Bs[b][i * 512]);
        }
    };

    STAGE(0); STAGE(1);                   // 32 outstanding

    const int T = K / 64;
    for (int t = 0; t < T; ++t) {
        if (t < T - 1) asm volatile("s_waitcnt vmcnt(16)" ::: "memory");
        else           asm volatile("s_waitcnt vmcnt(0)" ::: "memory");
        const short* Ab = As[t & 1];
        const short* Bb = Bs[t & 1];
        short8 af0[4], bf0[4], af1[4], bf1[4];
#pragma unroll
        for (int m = 0; m < 4; ++m) {
            const int R = m * 16 + lr;
            af0[m] = *(const short8*)&Ab[R * 64 + ((lg ^ (lr & 7)) * 8)];
            af1[m] = *(const short8*)&Ab[R * 64 + (((4 + lg) ^ (lr & 7)) * 8)];
            bf0[m] = *(const short8*)&Bb[R * 64 + ((lg ^ (lr & 7)) * 8)];
            bf1[m] = *(const short8*)&Bb[R * 64 + (((4 + lg) ^ (lr & 7)) * 8)];
        }
        asm volatile("s_waitcnt lgkmcnt(0)" ::: "memory");  // reads done
        if (t + 2 < T) STAGE(t + 2);       // safe: buffer fully consumed
        __builtin_amdgcn_sched_barrier(0);
#pragma unroll
        for (int m = 0; m < 4; ++m)
#pragma unroll
            for (int n = 0; n < 4; ++n)
                acc[m][n] = __builtin_amdgcn_mfma_f32_16x16x32_bf16(af0[m], bf0[n], acc[m][n], 0, 0, 0);
#pragma unroll
        for (int m = 0; m < 4; ++m)
#pragma unroll
            for (int n = 0; n < 4; ++n)
                acc[m][n] = __builtin_amdgcn_mfma_f32_16x16x32_bf16(af1[m], bf1[n], acc[m][n], 0, 0, 0);
    }

#pragma unroll
    for (int n = 0; n < 4; ++n) {
        const int col = bn * 64 + n * 16 + lr;
        float cs = 1.0f;
        if (MODE == 0 && colscale) cs = colscale[col];
#pragma unroll
        for (int m = 0; m < 4; ++m) {
#pragma unroll
            for (int rr = 0; rr < 4; ++rr) {
                const int row = bm * 64 + m * 16 + lg * 4 + rr;
                float v = acc[m][n][rr];
                const size_t o = (size_t)row * N + col;
                if (MODE == 0) {
                    Cb[o] = __float2bfloat16(v * cs);
                } else if (MODE == 1) {
                    v = 0.5f * v * (1.0f + erff(v * 0.70710678118654752f));
                    Cb[o] = __float2bfloat16(v);
                } else if (MODE == 2) {
                    Cf[o] += v;
                } else {
                    Cf[o] = v;
                }
            }
        }
    }
}

// ---------------- logits GEMM: 256x256, counted-vmcnt pipeline -------------
// (R12-verified: ~181us, MfmaUtil 31%, 0 conflicts — empirical best)
__global__ __launch_bounds__(512, 2) void gemm256l(const __hip_bfloat16* __restrict__ A,
                                                   const __hip_bfloat16* __restrict__ B,
                                                   float* __restrict__ C,
                                                   int M, int N, int K) {
    __shared__ short As[2][256 * 64];
    __shared__ short Bs[2][256 * 64];
    const int tid = threadIdx.x;
    const int w = tid >> 6, ln = tid & 63, lr = ln & 15, lg = ln >> 4;
    const int wm = w >> 2, wn = w & 3;
    const int GM = M / 256;              // 8

    const int nwg = gridDim.x;           // 1000
    const int cpx = nwg >> 3;            // 125
    const int wg = (blockIdx.x & 7) * cpx + (blockIdx.x >> 3);
    const int bm = wg % GM, bn = wg / GM;

    const int srow = tid >> 3;           // 0..63
    const int scol = (((tid & 7) ^ ((tid >> 3) & 7)) * 8);
    const __hip_bfloat16* Ag = A + (size_t)(bm * 256 + srow) * K + scol;
    const __hip_bfloat16* Bg = B + (size_t)(bn * 256 + srow) * K + scol;
    const int ldsb = w * 512;            // shorts; wave-uniform

    f32x4 acc[8][4] = {};

    auto STAGE = [&](int t) {
        const int b = t & 1;
        const size_t ko = (size_t)t * 64;
#pragma unroll
        for (int i = 0; i < 4; ++i) {
            gld16(Ag + (size_t)(i * 64) * K + ko, &As[b][i * 4096 + ldsb]);
            gld16(Bg + (size_t)(i * 64) * K + ko, &Bs[b][i * 4096 + ldsb]);
        }
    };

    STAGE(0); STAGE(1);                   // 16 vmem / wave outstanding

    const int T = K / 64;                 // 16
    for (int t = 0; t < T; ++t) {
        if (t < T - 1) asm volatile("s_waitcnt vmcnt(8)" ::: "memory");
        else           asm volatile("s_waitcnt vmcnt(0)" ::: "memory");
        __builtin_amdgcn_s_barrier();     // tile t present in buf[t&1]

        const short* Ab = As[t & 1];
        const short* Bb = Bs[t & 1];
        short8 af0[8], bf0[4], af1[8], bf1[4];
#pragma unroll
        for (int m = 0; m < 8; ++m) {
            const int R = wm * 128 + m * 16 + lr;
            af0[m] = *(const short8*)&Ab[R * 64 + ((lg ^ (lr & 7)) * 8)];
        }
#pragma unroll
        for (int n = 0; n < 4; ++n) {
            const int R = wn * 64 + n * 16 + lr;
            bf0[n] = *(const short8*)&Bb[R * 64 + ((lg ^ (lr & 7)) * 8)];
        }
        // kk0 MFMAs (compiler may overlap kk1 reads below with these)
#pragma unroll
        for (int m = 0; m < 8; ++m)
#pragma unroll
            for (int n = 0; n < 4; ++n)
                acc[m][n] = __builtin_amdgcn_mfma_f32_16x16x32_bf16(af0[m], bf0[n], acc[m][n], 0, 0, 0);
#pragma unroll
        for (int m = 0; m < 8; ++m) {
            const int R = wm * 128 + m * 16 + lr;
            af1[m] = *(const short8*)&Ab[R * 64 + (((4 + lg) ^ (lr & 7)) * 8)];
        }
#pragma unroll
        for (int n = 0; n < 4; ++n) {
            const int R = wn * 64 + n * 16 + lr;
            bf1[n] = *(const short8*)&Bb[R * 64 + (((4 + lg) ^ (lr & 7)) * 8)];
        }
        asm volatile("s_waitcnt lgkmcnt(0)" ::: "memory");
        __builtin_amdgcn_s_barrier();     // all waves done reading buf[t&1]
        if (t + 2 < T) STAGE(t + 2);      // overwrite buf[t&1] (safe)
        __builtin_amdgcn_sched_barrier(0);
        __builtin_amdgcn_s_setprio(1);
#pragma unroll
        for (int m = 0; m < 8; ++m)
#pragma unroll
            for (int n = 0; n < 4; ++n)
                acc[m][n] = __builtin_amdgcn_mfma_f32_16x16x32_bf16(af1[m], bf1[n], acc[m][n], 0, 0, 0);
        __builtin_amdgcn_s_setprio(0);
    }

#pragma unroll
    for (int m = 0; m < 8; ++m) {
        const int row = bm * 256 + wm * 128 + m * 16 + lg * 4;
#pragma unroll
        for (int rr = 0; rr < 4; ++rr) {
            float* crow = C + (size_t)(row + rr) * N + bn * 256 + wn * 64 + lr;
#pragma unroll
            for (int n = 0; n < 4; ++n)
                crow[n * 16] = acc[m][n][rr];
        }
    }
}

// ------------- per-head SVF U-projection (K=16) + layout fusion ------------
__global__ __launch_bounds__(256) void kqv2_k(const __hip_bfloat16* __restrict__ t1,
                                              const __hip_bfloat16* __restrict__ U,
                                              __hip_bfloat16* __restrict__ qb,
                                              __hip_bfloat16* __restrict__ kb2,
                                              __hip_bfloat16* __restrict__ vt2) {
    size_t i = (size_t)blockIdx.x * 256 + threadIdx.x; // 3*16*2048*64
    int s = (int)(i & 63);
    size_t rest = i >> 6;
    int t = (int)(rest & (T_SEQ - 1));
    int gh = (int)(rest >> 11);                        // 0..47, g-major
    const short8* trow = (const short8*)(t1 + (size_t)t * NKQV + gh * RH);
    const short8* urow = (const short8*)(U + ((size_t)gh * HSZ + s) * RH);
    short8 ta = trow[0], tb = trow[1];
    short8 ua = urow[0], ub = urow[1];
    float acc = 0.f;
#pragma unroll
    for (int j = 0; j < 8; ++j) {
        acc += bfbits2f((ushort_t)ta[j]) * bfbits2f((ushort_t)ua[j]);
        acc += bfbits2f((ushort_t)tb[j]) * bfbits2f((ushort_t)ub[j]);
    }
    const ushort_t val = f2bfu(acc);
    const int g = gh >> 4, h = gh & 15;               // block-uniform g
    if (g == 1) {
        ((ushort_t*)qb)[((size_t)h * T_SEQ + t) * HSZ + s] = val;
    } else if (g == 0) {
        const int tile = t >> 6, gg = (t >> 4) & 3, lr = t & 15;
        const int half = s >> 5, lg = (s >> 3) & 3, j = s & 7;
        const int c = gg * 2 + half, ln = lg * 16 + lr;
        ((ushort_t*)kb2)[(((size_t)h * 32 + tile) * 8 + c) * 512 + ln * 8 + j] = val;
    } else {
        const int tile = t >> 6, half = (t >> 5) & 1, lg2 = (t >> 3) & 3, j2 = t & 7;
        const int dt = s >> 4, lr2 = s & 15;
        const int c = dt * 2 + half, ln = lg2 * 16 + lr2;
        ((ushort_t*)vt2)[(((size_t)h * 32 + tile) * 8 + c) * 512 + ln * 8 + j2] = val;
    }
}

// --------------------------- MFMA flash attention --------------------------
// KVBLK=128, masked-tail pair + defer-max (T13). R22: V fragment loads for
// the CURRENT pair hoisted above the softmax chain so their latency overlaps
// softmax VALU + P roundtrip (they were pinned below the lgkmcnt clobber).
__global__ __launch_bounds__(256) void attn_k(const __hip_bfloat16* __restrict__ qb,
                                              const __hip_bfloat16* __restrict__ kb2,
                                              const __hip_bfloat16* __restrict__ vt2,
                                              __hip_bfloat16* __restrict__ attout) {
    __shared__ short P_s[2][4][16 * 136];  // [dbuf][wave][16 q x 128 u], stride 136
    const int tid = threadIdx.x, w = tid >> 6, ln = tid & 63;
    const int lr = ln & 15, lg = ln >> 4;
    const int f = blockIdx.y * 32 + blockIdx.x;
    const int h = ((f & 7) << 1) | ((f >> 3) & 1);
    const int bi = f >> 4;
    const int t0 = bi * 16 + w * 512;
    const size_t hb = (size_t)h * T_SEQ;
    const size_t hB = (size_t)h * 32;   // tile base for chunk addressing
    const float SCL = 0.18033688011112042f; // 0.125 * log2(e)

    short8 qf0 = *(const short8*)(qb + (hb + t0 + lr) * HSZ + lg * 8);
    short8 qf1 = *(const short8*)(qb + (hb + t0 + lr) * HSZ + 32 + lg * 8);

    f32x4 acc[4] = {};
    float mrun = -3e38f, lrun = 0.f;
    int pbuf = 0;

    short8 kf[8][2];
#pragma unroll
    for (int c = 0; c < 8; ++c) {
        kf[c][0] = *(const short8*)(kb2 + ((hB + (c >> 2)) * 8 + (c & 3) * 2 + 0) * 512 + (size_t)ln * 8);
        kf[c][1] = *(const short8*)(kb2 + ((hB + (c >> 2)) * 8 + (c & 3) * 2 + 1) * 512 + (size_t)ln * 8);
    }

    const int last = t0 >> 7;             // index of the final 128-pair
    for (int it2 = 0; it2 <= last; ++it2) {
        f32x4 st[8];
#pragma unroll
        for (int c = 0; c < 8; ++c) {
            f32x4 z = {};
            z = __builtin_amdgcn_mfma_f32_16x16x32_bf16(kf[c][0], qf0, z, 0, 0, 0);
            st[c] = __builtin_amdgcn_mfma_f32_16x16x32_bf16(kf[c][1], qf1, z, 0, 0, 0);
        }

        if (it2 < last) {                 // prefetch next K pair
            const int tn = (it2 + 1) * 2;
#pragma unroll
            for (int c = 0; c < 8; ++c) {
                kf[c][0] = *(const short8*)(kb2 + ((hB + tn + (c >> 2)) * 8 + (c & 3) * 2 + 0) * 512 + (size_t)ln * 8);
                kf[c][1] = *(const short8*)(kb2 + ((hB + tn + (c >> 2)) * 8 + (c & 3) * 2 + 1) * 512 + (size_t)ln * 8);
            }
        }

        // R22: V fragments for the CURRENT pair issued here (before softmax)
        short8 vfs[2][4][2];
#pragma unroll
        for (int s = 0; s < 2; ++s)
#pragma unroll
            for (int dt = 0; dt < 4; ++dt) {
                vfs[s][dt][0] = *(const short8*)(vt2 + ((hB + it2 * 2 + s) * 8 + dt * 2 + 0) * 512 + (size_t)ln * 8);
                vfs[s][dt][1] = *(const short8*)(vt2 + ((hB + it2 * 2 + s) * 8 + dt * 2 + 1) * 512 + (size_t)ln * 8);
            }

        float sv[32];
        if (it2 == last) {                // only the final pair needs masking
            const int u0 = it2 * 128;
            const int qg = t0 + lr;
#pragma unroll
            for (int c = 0; c < 8; ++c)
#pragma unroll
                for (int r = 0; r < 4; ++r) {
                    float v = st[c][r] * SCL;
                    if (u0 + c * 16 + lg * 4 + r > qg) v = -1e30f;
                    sv[c * 4 + r] = v;
                }
        } else {
#pragma unroll
            for (int c = 0; c < 8; ++c)
#pragma unroll
                for (int r = 0; r < 4; ++r)
                    sv[c * 4 + r] = st[c][r] * SCL;
        }

        float mm[8];
#pragma unroll
        for (int c = 0; c < 8; ++c)
            mm[c] = fmaxf(fmaxf(sv[c * 4], sv[c * 4 + 1]), fmaxf(sv[c * 4 + 2], sv[c * 4 + 3]));
        float tm = fmaxf(fmaxf(fmaxf(mm[0], mm[1]), fmaxf(mm[2], mm[3])),
                         fmaxf(fmaxf(mm[4], mm[5]), fmaxf(mm[6], mm[7])));
        tm = fmaxf(tm, __shfl_xor(tm, 16));
        tm = fmaxf(tm, __shfl_xor(tm, 32));

        if (!__all(tm - mrun <= 8.0f)) {  // defer-max (T13)
            const float mnew = fmaxf(mrun, tm);
            const float corr = exp2f(mrun - mnew);
            lrun *= corr;
#pragma unroll
            for (int dt = 0; dt < 4; ++dt) acc[dt] *= corr;
            mrun = mnew;
        }

        float pv[32];
        float ls = 0.f;
#pragma unroll
        for (int j = 0; j < 32; ++j) { pv[j] = exp2f(sv[j] - mrun); ls += pv[j]; }
        ls += __shfl_xor(ls, 16);
        ls += __shfl_xor(ls, 32);
        lrun += ls;

        uint_t* pw = (uint_t*)P_s[pbuf][w];
        const int wb = lr * 68 + lg * 2;
#pragma unroll
        for (int c = 0; c < 8; ++c) {
            pw[wb + c * 8 + 0] = pack2bf(pv[c * 4 + 0], pv[c * 4 + 1]);
            pw[wb + c * 8 + 1] = pack2bf(pv[c * 4 + 2], pv[c * 4 + 3]);
        }
        asm volatile("s_waitcnt lgkmcnt(0)" ::: "memory");

#pragma unroll
        for (int s = 0; s < 2; ++s) {
            short8 pf0 = *(const short8*)(&P_s[pbuf][w][lr * 136 + s * 64 + lg * 8]);
            short8 pf1 = *(const short8*)(&P_s[pbuf][w][lr * 136 + s * 64 + 32 + lg * 8]);
#pragma unroll
            for (int dt = 0; dt < 4; ++dt) {
                acc[dt] = __builtin_amdgcn_mfma_f32_16x16x32_bf16(vfs[s][dt][0], pf0, acc[dt], 0, 0, 0);
                acc[dt] = __builtin_amdgcn_mfma_f32_16x16x32_bf16(vfs[s][dt][1], pf1, acc[dt], 0, 0, 0);
            }
        }

        pbuf ^= 1;
    }

    const float inv = 1.f / lrun;
#pragma unroll
    for (int dt = 0; dt < 4; ++dt) {
#pragma unroll
        for (int r = 0; r < 4; r += 2) {
            uint_t pk = pack2bf(acc[dt][r] * inv, acc[dt][r + 1] * inv);
            *(uint_t*)(attout + (size_t)(t0 + lr) * DMODEL + h * HSZ + dt * 16 + lg * 4 + r) = pk;
        }
    }
}

// ---------------------------------------------------------------------------
extern "C" void kernel_launch(void* const* d_in, const int* in_sizes, int n_in,
                              void* d_out, int out_size, void* d_ws, size_t ws_size,
                              hipStream_t stream) {
    const int* idx = (const int*)d_in[0];
    const float* tok_emb = (const float*)d_in[1];
    const float* pos_emb = (const float*)d_in[2];
    const float* ln1_w = (const float*)d_in[3];
    const float* ln1_b = (const float*)d_in[4];
    const float* ln2_w = (const float*)d_in[5];
    const float* ln2_b = (const float*)d_in[6];
    const float* kqv_V = (const float*)d_in[7];
    const float* kqv_z = (const float*)d_in[8];
    const float* kqv_U = (const float*)d_in[9];
    const float* proj_V = (const float*)d_in[10];
    const float* proj_z = (const float*)d_in[11];
    const float* proj_U = (const float*)d_in[12];
    const float* f1_V = (const float*)d_in[13];
    const float* f1_z = (const float*)d_in[14];
    const float* f1_U = (const float*)d_in[15];
    const float* f2_V = (const float*)d_in[16];
    const float* f2_z = (const float*)d_in[17];
    const float* f2_U = (const float*)d_in[18];
    const float* lnf_w = (const float*)d_in[19];
    const float* lnf_b = (const float*)d_in[20];
    const float* lm_w = (const float*)d_in[21];

    // ---------------- workspace layout ----------------
    char* W = (char*)d_ws;
    float* x = (float*)W;                 W += (size_t)T_SEQ * DMODEL * 4;
    __hip_bfloat16* hbuf = (__hip_bfloat16*)W; W += (size_t)T_SEQ * DMODEL * 2;
    __hip_bfloat16* t1 = (__hip_bfloat16*)W;   W += (size_t)T_SEQ * NKQV * 2;
    __hip_bfloat16* qbuf = (__hip_bfloat16*)W; W += (size_t)NHEAD * T_SEQ * HSZ * 2;  // Q rows
    __hip_bfloat16* kb2 = (__hip_bfloat16*)W;  W += (size_t)NHEAD * T_SEQ * HSZ * 2;  // K chunk-tiled
    __hip_bfloat16* vt2 = (__hip_bfloat16*)W;  W += (size_t)NHEAD * HSZ * T_SEQ * 2;  // V^T chunk-tiled
    __hip_bfloat16* attb = (__hip_bfloat16*)W; W += (size_t)T_SEQ * DMODEL * 2;
    __hip_bfloat16* ffb = (__hip_bfloat16*)W;  W += (size_t)T_SEQ * FFDIM * 2;
    __hip_bfloat16* wkV = (__hip_bfloat16*)W;  W += (size_t)NLAYER * NKQV * DMODEL * 2;
    __hip_bfloat16* wkU = (__hip_bfloat16*)W;  W += (size_t)NLAYER * 3 * NHEAD * HSZ * RH * 2;
    __hip_bfloat16* wpV = (__hip_bfloat16*)W;  W += (size_t)NLAYER * RP * DMODEL * 2;
    __hip_bfloat16* wpU = (__hip_bfloat16*)W;  W += (size_t)NLAYER * DMODEL * RP * 2;
    __hip_bfloat16* w1V = (__hip_bfloat16*)W;  W += (size_t)NLAYER * RF * DMODEL * 2;
    __hip_bfloat16* w1U = (__hip_bfloat16*)W;  W += (size_t)NLAYER * FFDIM * RF * 2;
    __hip_bfloat16* w2V = (__hip_bfloat16*)W;  W += (size_t)NLAYER * RF * FFDIM * 2;
    __hip_bfloat16* w2U = (__hip_bfloat16*)W;  W += (size_t)NLAYER * DMODEL * RF * 2;
    __hip_bfloat16* wlm = (__hip_bfloat16*)W;  W += (size_t)VOCAB * DMODEL * 2;

    // batched weight conversion (one kernel)
    {
        CvtArgs a;
        a.s[0] = kqv_V;  a.d[0] = wkV;  a.n4[0] = (int)((size_t)NLAYER * NKQV * DMODEL / 4);
        a.s[1] = kqv_U;  a.d[1] = wkU;  a.n4[1] = (int)((size_t)NLAYER * 3 * NHEAD * HSZ * RH / 4);
        a.s[2] = proj_V; a.d[2] = wpV;  a.n4[2] = (int)((size_t)NLAYER * RP * DMODEL / 4);
        a.s[3] = proj_U; a.d[3] = wpU;  a.n4[3] = (int)((size_t)NLAYER * DMODEL * RP / 4);
        a.s[4] = f1_V;   a.d[4] = w1V;  a.n4[4] = (int)((size_t)NLAYER * RF * DMODEL / 4);
        a.s[5] = f1_U;   a.d[5] = w1U;  a.n4[5] = (int)((size_t)NLAYER * FFDIM * RF / 4);
        a.s[6] = f2_V;   a.d[6] = w2V;  a.n4[6] = (int)((size_t)NLAYER * RF * FFDIM / 4);
        a.s[7] = f2_U;   a.d[7] = w2U;  a.n4[7] = (int)((size_t)NLAYER * DMODEL * RF / 4);
        a.s[8] = lm_w;   a.d[8] = wlm;  a.n4[8] = (int)((size_t)VOCAB * DMODEL / 4);
        int total4 = 0;
        for (int k = 0; k < 9; ++k) total4 += a.n4[k];
        cvtall_k<<<dim3((total4 + 255) / 256), dim3(256), 0, stream>>>(a, total4);
    }

    embed_k<<<dim3(T_SEQ * DMODEL / 4 / 256), dim3(256), 0, stream>>>(idx, tok_emb, pos_emb, x);

    const int M = T_SEQ;
    for (int l = 0; l < NLAYER; ++l) {
        ln_k<<<dim3(T_SEQ), dim3(256), 0, stream>>>(x, ln1_w + l * DMODEL, ln1_b + l * DMODEL, hbuf);
        gemm1w<0><<<dim3((M / 64) * (NKQV / 64)), dim3(64), 0, stream>>>(
            hbuf, wkV + (size_t)l * NKQV * DMODEL, kqv_z + (size_t)l * NKQV,
            t1, nullptr, M, NKQV, DMODEL);
        kqv2_k<<<dim3(3 * NHEAD * T_SEQ * HSZ / 256), dim3(256), 0, stream>>>(
            t1, wkU + (size_t)l * 3 * NHEAD * HSZ * RH, qbuf, kb2, vt2);
        attn_k<<<dim3(T_SEQ / 64, NHEAD), dim3(256), 0, stream>>>(qbuf, kb2, vt2, attb);
        gemm1w<0><<<dim3((M / 64) * (RP / 64)), dim3(64), 0, stream>>>(
            attb, wpV + (size_t)l * RP * DMODEL, proj_z + (size_t)l * RP,
            t1, nullptr, M, RP, DMODEL);
        gemm_t<64, 64, 2><<<dim3((M / 64) * (DMODEL / 64)), dim3(256), 0, stream>>>(
            t1, wpU + (size_t)l * DMODEL * RP, nullptr,
            nullptr, x, M, DMODEL, RP);
        ln_k<<<dim3(T_SEQ), dim3(256), 0, stream>>>(x, ln2_w + l * DMODEL, ln2_b + l * DMODEL, hbuf);
        gemm1w<0><<<dim3((M / 64) * (RF / 64)), dim3(64), 0, stream>>>(
            hbuf, w1V + (size_t)l * RF * DMODEL, f1_z + (size_t)l * RF,
            t1, nullptr, M, RF, DMODEL);
        gemm_t<64, 64, 1><<<dim3((M / 64) * (FFDIM / 64)), dim3(256), 0, stream>>>(
            t1, w1U + (size_t)l * FFDIM * RF, nullptr,
            ffb, nullptr, M, FFDIM, RF);
        gemm1w<0><<<dim3((M / 64) * (RF / 64)), dim3(64), 0, stream>>>(
            ffb, w2V + (size_t)l * RF * FFDIM, f2_z + (size_t)l * RF,
            t1, nullptr, M, RF, FFDIM);
        gemm_t<64, 64, 2><<<dim3((M / 64) * (DMODEL / 64)), dim3(256), 0, stream>>>(
            t1, w2U + (size_t)l * DMODEL * RF, nullptr,
            nullptr, x, M, DMODEL, RF);
    }
    ln_k<<<dim3(T_SEQ), dim3(256), 0, stream>>>(x, lnf_w, lnf_b, hbuf);
    // logits: 256x256 counted-vmcnt pipeline, grid 8*125 = 1000 (div by 8)
    gemm256l<<<dim3((M / 256) * (VOCAB / 256)), dim3(512), 0, stream>>>(
        hbuf, wlm, (float*)d_out, M, VOCAB, DMODEL);
}